// Round 12
// baseline (481.823 us; speedup 1.0000x reference)
//
#include <hip/hip_runtime.h>
#include <stdint.h>

typedef __attribute__((ext_vector_type(8))) short short8;
typedef __attribute__((ext_vector_type(4))) float f32x4;

#define DEV static __device__ __forceinline__

DEV float b2f(unsigned short u) {
  unsigned x = ((unsigned)u) << 16;
  return __builtin_bit_cast(float, x);
}
DEV unsigned short f2b(float f) {
  unsigned x = __builtin_bit_cast(unsigned, f);
  return (unsigned short)((x + 0x7fffu + ((x >> 16) & 1u)) >> 16);
}
DEV void gload16(const unsigned short* g, unsigned short* l) {
  __builtin_amdgcn_global_load_lds((const __attribute__((address_space(1))) void*)g,
                                   (__attribute__((address_space(3))) void*)l, 16, 0, 0);
}
#define MFMA(a, b, c) __builtin_amdgcn_mfma_f32_16x16x32_bf16(a, b, c, 0, 0, 0)
#define BARRIER                          \
  asm volatile("" ::: "memory");         \
  __builtin_amdgcn_s_barrier();          \
  asm volatile("" ::: "memory")

// ---------------- fused fp32 -> bf16 convert (x, Wqkv, Wg, Wo -> one contiguous dst) ----
__global__ __launch_bounds__(256) void k_f2b4(const float* __restrict__ x,
                                              const float* __restrict__ wqkv,
                                              const float* __restrict__ wg,
                                              const float* __restrict__ wo,
                                              unsigned short* __restrict__ dst) {
  long gi = ((long)blockIdx.x * 256 + threadIdx.x) * 4;  // combined elem index
  const float* src;
  long off;
  if (gi < 16777216L) { src = x; off = gi; }
  else if (gi < 29360128L) { src = wqkv; off = gi - 16777216L; }
  else if (gi < 33554432L) { src = wg; off = gi - 29360128L; }
  else { src = wo; off = gi - 33554432L; }
  float4 f = *(const float4*)(src + off);
  ushort4 o;
  o.x = f2b(f.x); o.y = f2b(f.y); o.z = f2b(f.z); o.w = f2b(f.w);
  *(ushort4*)(dst + gi) = o;
}

// ------- 256x256-tile 8-wave bf16 GEMM, BK=32 triple-buffered single-barrier -------
// LDS: 3 buffers x 32 KiB (within a 128 KiB array; full array reused by the repack
// epilogue). Buffer = one K=32 tile: slot0 = A rows 0..127 (8 KiB), slot1 = B rows 0..127,
// slot2 = A rows 128..255, slot3 = B rows 128..255. Tile T reads buf T%3; stage(T+2) is
// issued at the TOP of tile T into buf (T+2)%3 (never live). Single counted wait per tile:
// end-of-tile vmcnt(4) drains stage(T+1) (issued top of T-1, lead = 2 full tiles) leaving
// stage(T+2)'s 4 loads in flight. ONE barrier per tile; no mid-tile waits -- the entire
// 12-ds_read + 32-MFMA body is a single compiler scheduling window (fine lgkmcnt interleave).
// Swizzle (64B rows): chunk ^= pos&3 -- bijective onto each 1 KiB frag region, conflict-free;
// applied via pre-swizzled global source (linear gload_lds dest) + same XOR on ds_read.
// vmcnt(0)+barrier after the loop: dangling tail DMAs must land before LDS is reused.
// MODE 0 epilogue (R9): activations in regs -> bf16 -> swizzled LDS repack -> coalesced
// 16B stores. XCD chunking: tm = xcd*4+(sub&3), tn = sub>>2 (A fetched once per XCD-L2).
template <int MODE>
__global__ __launch_bounds__(512, 2) void k_gemm(
    const unsigned short* __restrict__ A, const unsigned short* __restrict__ B0,
    const unsigned short* __restrict__ B1,
    unsigned short* __restrict__ o_q, unsigned short* __restrict__ o_k,
    unsigned short* __restrict__ o_v, unsigned short* __restrict__ o_g,
    float* __restrict__ o_f) {
  const int K = 2048, NT = 64;  // BK = 32
  __shared__ unsigned short sm[65536];  // 128 KiB; staging uses first 96 KiB
  int tid = threadIdx.x, w = tid >> 6, lane = tid & 63;
  int wm = w >> 2, wn = w & 3;
  int l15 = lane & 15, l4 = lane >> 4;
  int xcd = blockIdx.x & 7, sub = blockIdx.x >> 3;
  int tm = xcd * 4 + (sub & 3), tn = sub >> 2;
  int brow = tm << 8, bcol = tn << 8;
  const unsigned short* Ab = A + (size_t)brow * K;
  const unsigned short* Bb = (MODE == 1 || bcol < 6144) ? (B0 + (size_t)bcol * K)
                                                        : (B1 + (size_t)(bcol - 6144) * K);
  f32x4 acc[8][4];
#pragma unroll
  for (int m = 0; m < 8; m++)
#pragma unroll
    for (int n = 0; n < 4; n++) acc[m][n] = (f32x4)0.f;

  // ---- precomputed LDS read byte-offsets (within a 32 KiB buffer) ----
  int rdA[4], rdB[4];
  const int bslotb = (wn >> 1) ? 24576 : 8192;
  const int bposb = (wn & 1) * 64;
#pragma unroll
  for (int fi = 0; fi < 4; ++fi) {
    int posA = wm * 64 + fi * 16 + l15;
    rdA[fi] = posA * 64 + ((l4 ^ (posA & 3)) << 4);
    int posB = bposb + fi * 16 + l15;
    rdB[fi] = bslotb + posB * 64 + ((l4 ^ (posB & 3)) << 4);
  }
  // ---- persistent global stage pointers (1 gload / thread / slot) ----
  const unsigned short* gP[4];
  {
    int pos = tid >> 2, pb = tid & 3;
    int scol = (pb ^ (pos & 3)) << 3;
#pragma unroll
    for (int s = 0; s < 4; ++s) {
      const unsigned short* gb = (s & 1) ? Bb : Ab;
      int ro = (s >> 1) << 7;
      gP[s] = gb + (size_t)(ro + pos) * K + scol;
    }
  }
  const int dLb = tid * 16;  // byte offset within slot

  auto stage = [&](int bufbyte) {  // stage one full tile (4 slots) into buffer
#pragma unroll
    for (int s = 0; s < 4; ++s) {
      gload16(gP[s], (unsigned short*)((char*)sm + bufbyte + s * 8192 + dLb));
      gP[s] += 32;  // advance one K-tile (64 B)
    }
  };

  // prologue: tile0 -> buf0, tile1 -> buf1; wait for buf0
  stage(0);
  stage(32768);
  asm volatile("s_waitcnt vmcnt(4)" ::: "memory");
  BARRIER;

  int b0 = 0, b1 = 32768, b2 = 65536;
  for (int T = 0; T < NT; ++T) {
    stage(b2);  // tile T+2 (tail: sources run past panel but stay inside workspace)
    const char* smb = (const char*)sm + b0;
    short8 bfr[4], afA[4], afB[4];
#pragma unroll
    for (int nj = 0; nj < 4; ++nj) bfr[nj] = *(const short8*)(smb + rdB[nj]);
#pragma unroll
    for (int fi = 0; fi < 4; ++fi) afA[fi] = *(const short8*)(smb + rdA[fi]);
#pragma unroll
    for (int fi = 0; fi < 4; ++fi) afB[fi] = *(const short8*)(smb + (rdA[fi] + 16384));
    __builtin_amdgcn_s_setprio(1);
#pragma unroll
    for (int mi = 0; mi < 4; ++mi)
#pragma unroll
      for (int nj = 0; nj < 4; ++nj) acc[mi][nj] = MFMA(afA[mi], bfr[nj], acc[mi][nj]);
#pragma unroll
    for (int mi = 0; mi < 4; ++mi)
#pragma unroll
      for (int nj = 0; nj < 4; ++nj) acc[4 + mi][nj] = MFMA(afB[mi], bfr[nj], acc[4 + mi][nj]);
    __builtin_amdgcn_s_setprio(0);
    asm volatile("s_waitcnt vmcnt(4)" ::: "memory");  // drains tile T+1's stages
    BARRIER;
    int t = b0; b0 = b1; b1 = b2; b2 = t;  // rotate buffers
  }
  asm volatile("s_waitcnt vmcnt(0)" ::: "memory");  // land dangling DMAs before LDS reuse
  BARRIER;

  if (MODE == 0) {
    // ---- repack epilogue: activation in regs -> bf16 -> swizzled LDS [256][256] ----
#pragma unroll
    for (int mf = 0; mf < 8; ++mf) {
      int rowb = (mf >> 2) * 128 + wm * 64 + (mf & 3) * 16 + l4 * 4;
#pragma unroll
      for (int ni = 0; ni < 4; ++ni) {
        int cx = wn * 64 + ((ni ^ l4) << 4) + l15;  // col XOR l4<<4 (conflict-free)
        int colg = bcol + wn * 64 + ni * 16 + l15;
#pragma unroll
        for (int r = 0; r < 4; ++r) {
          float v = acc[mf][ni][r];
          float a = (colg < 6144) ? v / (1.f + __expf(-v))    // silu
                                  : 1.f / (1.f + __expf(-v)); // sigmoid
          sm[(rowb + r) * 256 + cx] = f2b(a);
        }
      }
    }
    BARRIER;
    // ---- coalesced readout: 16 iters x (16 rows x 32 16B-chunks) ----
    int rl0 = tid >> 5;        // 0..15
    int ch = (tid & 31) * 8;   // chunk col base
    int cg = bcol + ch;        // global col (block-uniform q/k/v vs gate)
    unsigned short* qkvb = nullptr;
    size_t hbase = 0;
    int off = 0;
    const bool isq = (cg < 6144);
    if (isq) {
      int hh = cg / 384, dd = cg - hh * 384;
      int sel = dd >> 7;
      off = dd & 127;
      qkvb = (sel == 0) ? o_q : (sel == 1) ? o_k : o_v;
      hbase = (size_t)hh * 4096;
    }
#pragma unroll
    for (int it = 0; it < 16; ++it) {
      int rl = it * 16 + rl0;
      int cx = ch ^ (((rl >> 2) & 3) << 4);
      short8 v8 = *(const short8*)(sm + rl * 256 + cx);
      int row = brow + rl;
      if (isq) {
        int b = row >> 12, t = row & 4095;
        *(short8*)(qkvb + ((size_t)b * 65536 + hbase + t) * 128 + off) = v8;
      } else {
        *(short8*)(o_g + (size_t)row * 2048 + (cg - 6144)) = v8;
      }
    }
  } else {
#pragma unroll
    for (int mf = 0; mf < 8; ++mf)
#pragma unroll
      for (int r = 0; r < 4; ++r) {
        int row = brow + (mf >> 2) * 128 + wm * 64 + (mf & 3) * 16 + l4 * 4 + r;
#pragma unroll
        for (int ni = 0; ni < 4; ++ni) {
          int col = bcol + wn * 64 + ni * 16 + l15;
          o_f[(size_t)row * 2048 + col] = acc[mf][ni][r];
        }
      }
  }
}

// ---------------- per-block KV contribution: kvT[e][d] = sum_t V[t][e] * K[t][d]*kd[t] ----------------
__global__ __launch_bounds__(256) void k_kvblk(const unsigned short* __restrict__ kk,
                                               const unsigned short* __restrict__ vv,
                                               const float* __restrict__ slope,
                                               unsigned short* __restrict__ kvT) {
  int gid = blockIdx.x;  // 512 = bh*16 + blk
  int bh = gid >> 4, blk = gid & 15;
  float s = slope[bh & 15];
  __shared__ unsigned short kT[128][72];
  __shared__ unsigned short vT[128][72];
  int tid = threadIdx.x, w = tid >> 6, lane = tid & 63;
  int wrow = (w >> 1) * 64, wcol = (w & 1) * 64;
  f32x4 acc[4][4];
#pragma unroll
  for (int m = 0; m < 4; m++)
#pragma unroll
    for (int n = 0; n < 4; n++) acc[m][n] = (f32x4)0.f;
  const unsigned short* kb = kk + ((size_t)bh * 4096 + blk * 256) * 128;
  const unsigned short* vb = vv + ((size_t)bh * 4096 + blk * 256) * 128;
  int tt = tid & 63, c0 = (tid >> 6) * 32;
  for (int tc = 0; tc < 4; ++tc) {
    __syncthreads();
    int tg = tc * 64 + tt;
    float kd = __expf(-s * (float)(255 - tg));
#pragma unroll
    for (int g = 0; g < 4; ++g) {
      int c = c0 + g * 8;
      short8 k8 = *(const short8*)(kb + (size_t)tg * 128 + c);
      short8 v8 = *(const short8*)(vb + (size_t)tg * 128 + c);
#pragma unroll
      for (int j = 0; j < 8; ++j) {
        kT[c + j][tt] = f2b(b2f((unsigned short)k8[j]) * kd);
        vT[c + j][tt] = (unsigned short)v8[j];
      }
    }
    __syncthreads();
#pragma unroll
    for (int kx = 0; kx < 64; kx += 32) {
      int ko = kx + (lane >> 4) * 8;
      short8 af[4], bfr[4];
#pragma unroll
      for (int m = 0; m < 4; m++) af[m] = *(const short8*)&vT[wrow + m * 16 + (lane & 15)][ko];
#pragma unroll
      for (int n = 0; n < 4; n++) bfr[n] = *(const short8*)&kT[wcol + n * 16 + (lane & 15)][ko];
#pragma unroll
      for (int m = 0; m < 4; m++)
#pragma unroll
        for (int n = 0; n < 4; n++) acc[m][n] = MFMA(af[m], bfr[n], acc[m][n]);
    }
  }
  unsigned short* op = kvT + (size_t)gid * 16384;
#pragma unroll
  for (int m = 0; m < 4; m++)
#pragma unroll
    for (int r = 0; r < 4; r++) {
      int e = wrow + m * 16 + (lane >> 4) * 4 + r;
#pragma unroll
      for (int n = 0; n < 4; n++) {
        int d = wcol + n * 16 + (lane & 15);
        op[e * 128 + d] = f2b(acc[m][n][r]);
      }
    }
}

// ---------------- decay prefix scan over blocks (in place: kvT[i] := state before block i) ----------------
__global__ void k_scan(unsigned short* kvT, const float* __restrict__ slope) {
  int gid = blockIdx.x;  // 2048
  int bh = gid >> 6;
  int eo = (gid & 63) * 256 + threadIdx.x;  // 0..16383
  float s = slope[bh & 15];
  float bd = __expf(-s * 256.f);
  float st = 0.f;
  size_t base = (size_t)bh * 16 * 16384 + eo;
#pragma unroll
  for (int i = 0; i < 16; ++i) {
    unsigned short c = kvT[base + (size_t)i * 16384];
    kvT[base + (size_t)i * 16384] = f2b(st);
    st = bd * st + b2f(c);
  }
}

// ---------------- per-block attention output ----------------
__global__ __launch_bounds__(256) void k_attn(const unsigned short* __restrict__ q,
                                              const unsigned short* __restrict__ kk,
                                              const unsigned short* __restrict__ vv,
                                              const unsigned short* __restrict__ kvT,
                                              const float* __restrict__ slope,
                                              unsigned short* __restrict__ attn) {
  int gid = blockIdx.x;  // 1024 = (bh*16 + blk)*2 + hf
  int hf = gid & 1, blk = (gid >> 1) & 15, bh = gid >> 5;
  float s = slope[bh & 15];
  __shared__ unsigned short k_sh[64][136];
  __shared__ unsigned short vT_sh[128][72];
  __shared__ unsigned short s_sh[4][32][72];
  int tid = threadIdx.x, w = tid >> 6, lane = tid & 63;
  int mm0 = hf * 128 + w * 32;  // wave's first within-block row
  const unsigned short* qb = q + ((size_t)bh * 4096 + blk * 256) * 128;
  const unsigned short* kvb = kvT + (size_t)(bh * 16 + blk) * 16384;
  f32x4 acc[2][8];
#pragma unroll
  for (int m = 0; m < 2; m++)
#pragma unroll
    for (int n = 0; n < 8; n++) acc[m][n] = (f32x4)0.f;
  // inter-block: (q) @ KV_pre   (row-scale by q_decay afterwards)
#pragma unroll
  for (int kx = 0; kx < 128; kx += 32) {
    int ko = kx + (lane >> 4) * 8;
    short8 af[2], bfr[8];
#pragma unroll
    for (int mi = 0; mi < 2; mi++)
      af[mi] = *(const short8*)(qb + (size_t)(mm0 + mi * 16 + (lane & 15)) * 128 + ko);
#pragma unroll
    for (int ni = 0; ni < 8; ni++)
      bfr[ni] = *(const short8*)(kvb + (size_t)(ni * 16 + (lane & 15)) * 128 + ko);
#pragma unroll
    for (int mi = 0; mi < 2; mi++)
#pragma unroll
      for (int ni = 0; ni < 8; ni++) acc[mi][ni] = MFMA(af[mi], bfr[ni], acc[mi][ni]);
  }
#pragma unroll
  for (int mi = 0; mi < 2; mi++)
#pragma unroll
    for (int r = 0; r < 4; r++) {
      float qd = __expf(-s * (float)(mm0 + mi * 16 + (lane >> 4) * 4 + r + 1));
#pragma unroll
      for (int ni = 0; ni < 8; ni++) acc[mi][ni][r] *= qd;
    }
  // intra-block: masked quadratic attention, 64-wide t-chunks
  int nchunk = 2 * (hf + 1);
  for (int tc = 0; tc < nchunk; ++tc) {
    __syncthreads();
    {  // stage K chunk rows [t][d]
      int t2 = tid >> 2, c = (tid & 3) * 32;
      const unsigned short* kp = kk + ((size_t)bh * 4096 + blk * 256 + tc * 64 + t2) * 128 + c;
#pragma unroll
      for (int g = 0; g < 4; ++g) *(short8*)&k_sh[t2][c + g * 8] = *(const short8*)(kp + g * 8);
    }
    {  // stage V^T chunk [e][t]
      int t2 = tid & 63, e0 = (tid >> 6) * 32;
      const unsigned short* vp = vv + ((size_t)bh * 4096 + blk * 256 + tc * 64 + t2) * 128 + e0;
#pragma unroll
      for (int g = 0; g < 4; ++g) {
        short8 v8 = *(const short8*)(vp + g * 8);
#pragma unroll
        for (int j = 0; j < 8; ++j) vT_sh[e0 + g * 8 + j][t2] = (unsigned short)v8[j];
      }
    }
    __syncthreads();
    if (tc * 64 <= mm0 + 31) {
      f32x4 sa[2][4];
#pragma unroll
      for (int m = 0; m < 2; m++)
#pragma unroll
        for (int n = 0; n < 4; n++) sa[m][n] = (f32x4)0.f;
#pragma unroll
      for (int kx = 0; kx < 128; kx += 32) {
        int ko = kx + (lane >> 4) * 8;
        short8 af[2], bfr[4];
#pragma unroll
        for (int mi = 0; mi < 2; mi++)
          af[mi] = *(const short8*)(qb + (size_t)(mm0 + mi * 16 + (lane & 15)) * 128 + ko);
#pragma unroll
        for (int ni = 0; ni < 4; ni++) bfr[ni] = *(const short8*)&k_sh[ni * 16 + (lane & 15)][ko];
#pragma unroll
        for (int mi = 0; mi < 2; mi++)
#pragma unroll
          for (int ni = 0; ni < 4; ni++) sa[mi][ni] = MFMA(af[mi], bfr[ni], sa[mi][ni]);
      }
      // mask * decay, to bf16, into per-wave S tile
#pragma unroll
      for (int mi = 0; mi < 2; mi++)
#pragma unroll
        for (int ni = 0; ni < 4; ni++)
#pragma unroll
          for (int r = 0; r < 4; r++) {
            int mm = mm0 + mi * 16 + (lane >> 4) * 4 + r;
            int ttg = tc * 64 + ni * 16 + (lane & 15);
            int diff = mm - ttg;
            float val = (diff >= 0) ? sa[mi][ni][r] * __expf(-s * (float)diff) : 0.f;
            s_sh[w][mi * 16 + (lane >> 4) * 4 + r][ni * 16 + (lane & 15)] = f2b(val);
          }
      // O += S @ V
#pragma unroll
      for (int k2 = 0; k2 < 64; k2 += 32) {
        int ko2 = k2 + (lane >> 4) * 8;
        short8 a2[2];
#pragma unroll
        for (int mi = 0; mi < 2; mi++)
          a2[mi] = *(const short8*)&s_sh[w][mi * 16 + (lane & 15)][ko2];
#pragma unroll
        for (int ni = 0; ni < 8; ni++) {
          short8 b2 = *(const short8*)&vT_sh[ni * 16 + (lane & 15)][ko2];
#pragma unroll
          for (int mi = 0; mi < 2; mi++) acc[mi][ni] = MFMA(a2[mi], b2, acc[mi][ni]);
        }
      }
    }
  }
  int b = bh >> 4, h = bh & 15;
#pragma unroll
  for (int mi = 0; mi < 2; mi++)
#pragma unroll
    for (int r = 0; r < 4; r++) {
      int mm = mm0 + mi * 16 + (lane >> 4) * 4 + r;
      size_t rowp = ((size_t)b * 4096 + blk * 256 + mm) * 2048 + h * 128;
#pragma unroll
      for (int ni = 0; ni < 8; ni++) attn[rowp + ni * 16 + (lane & 15)] = f2b(acc[mi][ni][r]);
    }
}

// ---------------- RMSNorm + gate ----------------
__global__ __launch_bounds__(256) void k_norm(const unsigned short* __restrict__ attn,
                                              const unsigned short* __restrict__ gate,
                                              const float* __restrict__ nw,
                                              unsigned short* __restrict__ y) {
  int row = blockIdx.x;  // 8192
  int tid = threadIdx.x, w = tid >> 6, lane = tid & 63;
  const unsigned short* ap = attn + (size_t)row * 2048 + tid * 8;
  const unsigned short* gp = gate + (size_t)row * 2048 + tid * 8;
  short8 a8 = *(const short8*)ap;
  float vals[8];
  float ss = 0.f;
#pragma unroll
  for (int j = 0; j < 8; ++j) {
    vals[j] = b2f((unsigned short)a8[j]);
    ss += vals[j] * vals[j];
  }
#pragma unroll
  for (int off = 32; off > 0; off >>= 1) ss += __shfl_down(ss, off, 64);
  __shared__ float red[4];
  if (lane == 0) red[w] = ss;
  __syncthreads();
  float tot = red[0] + red[1] + red[2] + red[3];
  float rms = rsqrtf(tot * (1.f / 2048.f) + 1.1920929e-07f);
  short8 g8 = *(const short8*)gp;
  short8 o;
#pragma unroll
  for (int j = 0; j < 8; ++j)
    o[j] = (short)f2b(vals[j] * rms * nw[tid * 8 + j] * b2f((unsigned short)g8[j]));
  *(short8*)(y + (size_t)row * 2048 + tid * 8) = o;
}

extern "C" void kernel_launch(void* const* d_in, const int* in_sizes, int n_in, void* d_out,
                              int out_size, void* d_ws, size_t ws_size, hipStream_t stream) {
  const float* x = (const float*)d_in[0];
  const float* slope = (const float*)d_in[1];
  const float* Wqkv = (const float*)d_in[2];
  const float* Wg = (const float*)d_in[3];
  const float* nw = (const float*)d_in[4];
  const float* Wo = (const float*)d_in[5];
  float* out = (float*)d_out;

  unsigned short* q = (unsigned short*)d_ws;               // 16,777,216 elems
  unsigned short* k = q + 16777216;                        // 16,777,216
  unsigned short* v = k + 16777216;                        // 16,777,216
  unsigned short* gate = v + 16777216;                     // 16,777,216
  unsigned short* xb = gate + 16777216;                    // 16,777,216
  unsigned short* wqkvb = xb + 16777216;                   // 12,582,912
  unsigned short* wgb = wqkvb + 12582912;                  // 4,194,304
  unsigned short* wob = wgb + 4194304;                     // 4,194,304
  unsigned short* kvT = wob + 4194304;                     // 8,388,608
  unsigned short* attn = wqkvb;  // alias: wqkvb+wgb dead after GEMM1 (exactly 16,777,216)
  unsigned short* y = xb;        // alias: xb dead after GEMM1

  k_f2b4<<<36864, 256, 0, stream>>>(x, Wqkv, Wg, Wo, xb);  // xb..wob contiguous

  k_gemm<0><<<1024, 512, 0, stream>>>(xb, wqkvb, wgb, q, k, v, gate, nullptr);
  k_kvblk<<<512, 256, 0, stream>>>(k, v, slope, kvT);
  k_scan<<<2048, 256, 0, stream>>>(kvT, slope);
  k_attn<<<1024, 256, 0, stream>>>(q, k, v, kvT, slope, attn);
  k_norm<<<8192, 256, 0, stream>>>(attn, gate, nw, y);
  k_gemm<1><<<256, 512, 0, stream>>>(y, wob, nullptr, nullptr, nullptr, nullptr, nullptr, out);
}

// Round 13
// 469.851 us; speedup vs baseline: 1.0255x; 1.0255x over previous
//
#include <hip/hip_runtime.h>
#include <stdint.h>

typedef __attribute__((ext_vector_type(8))) short short8;
typedef __attribute__((ext_vector_type(4))) float f32x4;

#define DEV static __device__ __forceinline__

DEV float b2f(unsigned short u) {
  unsigned x = ((unsigned)u) << 16;
  return __builtin_bit_cast(float, x);
}
DEV unsigned short f2b(float f) {
  unsigned x = __builtin_bit_cast(unsigned, f);
  return (unsigned short)((x + 0x7fffu + ((x >> 16) & 1u)) >> 16);
}
DEV void gload16(const unsigned short* g, unsigned short* l) {
  __builtin_amdgcn_global_load_lds((const __attribute__((address_space(1))) void*)g,
                                   (__attribute__((address_space(3))) void*)l, 16, 0, 0);
}
#define MFMA(a, b, c) __builtin_amdgcn_mfma_f32_16x16x32_bf16(a, b, c, 0, 0, 0)
#define BARRIER                          \
  asm volatile("" ::: "memory");         \
  __builtin_amdgcn_s_barrier();          \
  asm volatile("" ::: "memory")

// ---------------- fused fp32 -> bf16 convert (x, Wqkv, Wg, Wo -> one contiguous dst) ----
__global__ __launch_bounds__(256) void k_f2b4(const float* __restrict__ x,
                                              const float* __restrict__ wqkv,
                                              const float* __restrict__ wg,
                                              const float* __restrict__ wo,
                                              unsigned short* __restrict__ dst) {
  long gi = ((long)blockIdx.x * 256 + threadIdx.x) * 4;  // combined elem index
  const float* src;
  long off;
  if (gi < 16777216L) { src = x; off = gi; }
  else if (gi < 29360128L) { src = wqkv; off = gi - 16777216L; }
  else if (gi < 33554432L) { src = wg; off = gi - 29360128L; }
  else { src = wo; off = gi - 33554432L; }
  float4 f = *(const float4*)(src + off);
  ushort4 o;
  o.x = f2b(f.x); o.y = f2b(f.y); o.z = f2b(f.z); o.w = f2b(f.w);
  *(ushort4*)(dst + gi) = o;
}

// ------- 256x256-tile 8-wave bf16 GEMM, BK=32 triple-buffered single-barrier -------
// LDS: 3 buffers x 32 KiB. Buffer = one K=32 tile: slot0 = A rows 0..127, slot1 = B rows
// 0..127, slot2 = A rows 128..255, slot3 = B rows 128..255. Tile T reads buf T%3; stage(T+2)
// issued at TOP of tile T into buf (T+2)%3 (never live). vmcnt(4) at tile end drains
// stage(T+1) (lead = 2 full tiles); ONE barrier per tile; no mid-tile waits.
// Swizzle (64B rows, 16-bank row stride): bank(row,chunk) = (16*(row&1)+4*chunk)%32 -- only
// (row parity, chunk) matters. chunk = l4 ^ ((row>>1)&3) gives each 4-bank slot exactly 2
// lanes per 16-lane group (2-way = free). [R12's chunk = l4^(row&3) repeated every 4 rows ->
// 4-way conflict, 2.5e7 SQ_LDS_BANK_CONFLICT, +40us.] Applied via pre-swizzled global
// source (linear gload_lds dest) + same XOR on ds_read.
// vmcnt(0)+barrier after loop: dangling tail DMAs land before LDS reuse.
// MODE 0 epilogue (R9): activations in regs -> bf16 -> swizzled LDS repack -> coalesced
// 16B stores. XCD chunking: tm = xcd*4+(sub&3), tn = sub>>2 (A fetched once per XCD-L2).
template <int MODE>
__global__ __launch_bounds__(512, 2) void k_gemm(
    const unsigned short* __restrict__ A, const unsigned short* __restrict__ B0,
    const unsigned short* __restrict__ B1,
    unsigned short* __restrict__ o_q, unsigned short* __restrict__ o_k,
    unsigned short* __restrict__ o_v, unsigned short* __restrict__ o_g,
    float* __restrict__ o_f) {
  const int K = 2048, NT = 64;  // BK = 32
  __shared__ unsigned short sm[65536];  // 128 KiB; staging uses first 96 KiB
  int tid = threadIdx.x, w = tid >> 6, lane = tid & 63;
  int wm = w >> 2, wn = w & 3;
  int l15 = lane & 15, l4 = lane >> 4;
  int xcd = blockIdx.x & 7, sub = blockIdx.x >> 3;
  int tm = xcd * 4 + (sub & 3), tn = sub >> 2;
  int brow = tm << 8, bcol = tn << 8;
  const unsigned short* Ab = A + (size_t)brow * K;
  const unsigned short* Bb = (MODE == 1 || bcol < 6144) ? (B0 + (size_t)bcol * K)
                                                        : (B1 + (size_t)(bcol - 6144) * K);
  f32x4 acc[8][4];
#pragma unroll
  for (int m = 0; m < 8; m++)
#pragma unroll
    for (int n = 0; n < 4; n++) acc[m][n] = (f32x4)0.f;

  // ---- precomputed LDS read byte-offsets (within a 32 KiB buffer) ----
  int rdA[4], rdB[4];
  const int bslotb = (wn >> 1) ? 24576 : 8192;
  const int bposb = (wn & 1) * 64;
#pragma unroll
  for (int fi = 0; fi < 4; ++fi) {
    int posA = wm * 64 + fi * 16 + l15;
    rdA[fi] = posA * 64 + ((l4 ^ ((posA >> 1) & 3)) << 4);
    int posB = bposb + fi * 16 + l15;
    rdB[fi] = bslotb + posB * 64 + ((l4 ^ ((posB >> 1) & 3)) << 4);
  }
  // ---- persistent global stage pointers (1 gload / thread / slot) ----
  const unsigned short* gP[4];
  {
    int pos = tid >> 2, pb = tid & 3;
    int scol = (pb ^ ((pos >> 1) & 3)) << 3;
#pragma unroll
    for (int s = 0; s < 4; ++s) {
      const unsigned short* gb = (s & 1) ? Bb : Ab;
      int ro = (s >> 1) << 7;
      gP[s] = gb + (size_t)(ro + pos) * K + scol;
    }
  }
  const int dLb = tid * 16;  // byte offset within slot

  auto stage = [&](int bufbyte) {  // stage one full tile (4 slots) into buffer
#pragma unroll
    for (int s = 0; s < 4; ++s) {
      gload16(gP[s], (unsigned short*)((char*)sm + bufbyte + s * 8192 + dLb));
      gP[s] += 32;  // advance one K-tile (64 B)
    }
  };

  // prologue: tile0 -> buf0, tile1 -> buf1; wait for buf0
  stage(0);
  stage(32768);
  asm volatile("s_waitcnt vmcnt(4)" ::: "memory");
  BARRIER;

  int b0 = 0, b1 = 32768, b2 = 65536;
  for (int T = 0; T < NT; ++T) {
    stage(b2);  // tile T+2 (tail: sources run past panel but stay inside workspace)
    const char* smb = (const char*)sm + b0;
    short8 bfr[4], afA[4], afB[4];
#pragma unroll
    for (int nj = 0; nj < 4; ++nj) bfr[nj] = *(const short8*)(smb + rdB[nj]);
#pragma unroll
    for (int fi = 0; fi < 4; ++fi) afA[fi] = *(const short8*)(smb + rdA[fi]);
#pragma unroll
    for (int fi = 0; fi < 4; ++fi) afB[fi] = *(const short8*)(smb + (rdA[fi] + 16384));
    __builtin_amdgcn_s_setprio(1);
#pragma unroll
    for (int mi = 0; mi < 4; ++mi)
#pragma unroll
      for (int nj = 0; nj < 4; ++nj) acc[mi][nj] = MFMA(afA[mi], bfr[nj], acc[mi][nj]);
#pragma unroll
    for (int mi = 0; mi < 4; ++mi)
#pragma unroll
      for (int nj = 0; nj < 4; ++nj) acc[4 + mi][nj] = MFMA(afB[mi], bfr[nj], acc[4 + mi][nj]);
    __builtin_amdgcn_s_setprio(0);
    asm volatile("s_waitcnt vmcnt(4)" ::: "memory");  // drains tile T+1's stages
    BARRIER;
    int t = b0; b0 = b1; b1 = b2; b2 = t;  // rotate buffers
  }
  asm volatile("s_waitcnt vmcnt(0)" ::: "memory");  // land dangling DMAs before LDS reuse
  BARRIER;

  if (MODE == 0) {
    // ---- repack epilogue: activation in regs -> bf16 -> swizzled LDS [256][256] ----
#pragma unroll
    for (int mf = 0; mf < 8; ++mf) {
      int rowb = (mf >> 2) * 128 + wm * 64 + (mf & 3) * 16 + l4 * 4;
#pragma unroll
      for (int ni = 0; ni < 4; ++ni) {
        int cx = wn * 64 + ((ni ^ l4) << 4) + l15;  // col XOR l4<<4 (conflict-free)
        int colg = bcol + wn * 64 + ni * 16 + l15;
#pragma unroll
        for (int r = 0; r < 4; ++r) {
          float v = acc[mf][ni][r];
          float a = (colg < 6144) ? v / (1.f + __expf(-v))    // silu
                                  : 1.f / (1.f + __expf(-v)); // sigmoid
          sm[(rowb + r) * 256 + cx] = f2b(a);
        }
      }
    }
    BARRIER;
    // ---- coalesced readout: 16 iters x (16 rows x 32 16B-chunks) ----
    int rl0 = tid >> 5;        // 0..15
    int ch = (tid & 31) * 8;   // chunk col base
    int cg = bcol + ch;        // global col (block-uniform q/k/v vs gate)
    unsigned short* qkvb = nullptr;
    size_t hbase = 0;
    int off = 0;
    const bool isq = (cg < 6144);
    if (isq) {
      int hh = cg / 384, dd = cg - hh * 384;
      int sel = dd >> 7;
      off = dd & 127;
      qkvb = (sel == 0) ? o_q : (sel == 1) ? o_k : o_v;
      hbase = (size_t)hh * 4096;
    }
#pragma unroll
    for (int it = 0; it < 16; ++it) {
      int rl = it * 16 + rl0;
      int cx = ch ^ (((rl >> 2) & 3) << 4);
      short8 v8 = *(const short8*)(sm + rl * 256 + cx);
      int row = brow + rl;
      if (isq) {
        int b = row >> 12, t = row & 4095;
        *(short8*)(qkvb + ((size_t)b * 65536 + hbase + t) * 128 + off) = v8;
      } else {
        *(short8*)(o_g + (size_t)row * 2048 + (cg - 6144)) = v8;
      }
    }
  } else {
#pragma unroll
    for (int mf = 0; mf < 8; ++mf)
#pragma unroll
      for (int r = 0; r < 4; ++r) {
        int row = brow + (mf >> 2) * 128 + wm * 64 + (mf & 3) * 16 + l4 * 4 + r;
#pragma unroll
        for (int ni = 0; ni < 4; ++ni) {
          int col = bcol + wn * 64 + ni * 16 + l15;
          o_f[(size_t)row * 2048 + col] = acc[mf][ni][r];
        }
      }
  }
}

// ---------------- per-block KV contribution: kvT[e][d] = sum_t V[t][e] * K[t][d]*kd[t] ----------------
__global__ __launch_bounds__(256) void k_kvblk(const unsigned short* __restrict__ kk,
                                               const unsigned short* __restrict__ vv,
                                               const float* __restrict__ slope,
                                               unsigned short* __restrict__ kvT) {
  int gid = blockIdx.x;  // 512 = bh*16 + blk
  int bh = gid >> 4, blk = gid & 15;
  float s = slope[bh & 15];
  __shared__ unsigned short kT[128][72];
  __shared__ unsigned short vT[128][72];
  int tid = threadIdx.x, w = tid >> 6, lane = tid & 63;
  int wrow = (w >> 1) * 64, wcol = (w & 1) * 64;
  f32x4 acc[4][4];
#pragma unroll
  for (int m = 0; m < 4; m++)
#pragma unroll
    for (int n = 0; n < 4; n++) acc[m][n] = (f32x4)0.f;
  const unsigned short* kb = kk + ((size_t)bh * 4096 + blk * 256) * 128;
  const unsigned short* vb = vv + ((size_t)bh * 4096 + blk * 256) * 128;
  int tt = tid & 63, c0 = (tid >> 6) * 32;
  for (int tc = 0; tc < 4; ++tc) {
    __syncthreads();
    int tg = tc * 64 + tt;
    float kd = __expf(-s * (float)(255 - tg));
#pragma unroll
    for (int g = 0; g < 4; ++g) {
      int c = c0 + g * 8;
      short8 k8 = *(const short8*)(kb + (size_t)tg * 128 + c);
      short8 v8 = *(const short8*)(vb + (size_t)tg * 128 + c);
#pragma unroll
      for (int j = 0; j < 8; ++j) {
        kT[c + j][tt] = f2b(b2f((unsigned short)k8[j]) * kd);
        vT[c + j][tt] = (unsigned short)v8[j];
      }
    }
    __syncthreads();
#pragma unroll
    for (int kx = 0; kx < 64; kx += 32) {
      int ko = kx + (lane >> 4) * 8;
      short8 af[4], bfr[4];
#pragma unroll
      for (int m = 0; m < 4; m++) af[m] = *(const short8*)&vT[wrow + m * 16 + (lane & 15)][ko];
#pragma unroll
      for (int n = 0; n < 4; n++) bfr[n] = *(const short8*)&kT[wcol + n * 16 + (lane & 15)][ko];
#pragma unroll
      for (int m = 0; m < 4; m++)
#pragma unroll
        for (int n = 0; n < 4; n++) acc[m][n] = MFMA(af[m], bfr[n], acc[m][n]);
    }
  }
  unsigned short* op = kvT + (size_t)gid * 16384;
#pragma unroll
  for (int m = 0; m < 4; m++)
#pragma unroll
    for (int r = 0; r < 4; r++) {
      int e = wrow + m * 16 + (lane >> 4) * 4 + r;
#pragma unroll
      for (int n = 0; n < 4; n++) {
        int d = wcol + n * 16 + (lane & 15);
        op[e * 128 + d] = f2b(acc[m][n][r]);
      }
    }
}

// ---------------- decay prefix scan over blocks (in place: kvT[i] := state before block i) ----------------
__global__ void k_scan(unsigned short* kvT, const float* __restrict__ slope) {
  int gid = blockIdx.x;  // 2048
  int bh = gid >> 6;
  int eo = (gid & 63) * 256 + threadIdx.x;  // 0..16383
  float s = slope[bh & 15];
  float bd = __expf(-s * 256.f);
  float st = 0.f;
  size_t base = (size_t)bh * 16 * 16384 + eo;
#pragma unroll
  for (int i = 0; i < 16; ++i) {
    unsigned short c = kvT[base + (size_t)i * 16384];
    kvT[base + (size_t)i * 16384] = f2b(st);
    st = bd * st + b2f(c);
  }
}

// ---------------- per-block attention output ----------------
__global__ __launch_bounds__(256) void k_attn(const unsigned short* __restrict__ q,
                                              const unsigned short* __restrict__ kk,
                                              const unsigned short* __restrict__ vv,
                                              const unsigned short* __restrict__ kvT,
                                              const float* __restrict__ slope,
                                              unsigned short* __restrict__ attn) {
  int gid = blockIdx.x;  // 1024 = (bh*16 + blk)*2 + hf
  int hf = gid & 1, blk = (gid >> 1) & 15, bh = gid >> 5;
  float s = slope[bh & 15];
  __shared__ unsigned short k_sh[64][136];
  __shared__ unsigned short vT_sh[128][72];
  __shared__ unsigned short s_sh[4][32][72];
  int tid = threadIdx.x, w = tid >> 6, lane = tid & 63;
  int mm0 = hf * 128 + w * 32;  // wave's first within-block row
  const unsigned short* qb = q + ((size_t)bh * 4096 + blk * 256) * 128;
  const unsigned short* kvb = kvT + (size_t)(bh * 16 + blk) * 16384;
  f32x4 acc[2][8];
#pragma unroll
  for (int m = 0; m < 2; m++)
#pragma unroll
    for (int n = 0; n < 8; n++) acc[m][n] = (f32x4)0.f;
  // inter-block: (q) @ KV_pre   (row-scale by q_decay afterwards)
#pragma unroll
  for (int kx = 0; kx < 128; kx += 32) {
    int ko = kx + (lane >> 4) * 8;
    short8 af[2], bfr[8];
#pragma unroll
    for (int mi = 0; mi < 2; mi++)
      af[mi] = *(const short8*)(qb + (size_t)(mm0 + mi * 16 + (lane & 15)) * 128 + ko);
#pragma unroll
    for (int ni = 0; ni < 8; ni++)
      bfr[ni] = *(const short8*)(kvb + (size_t)(ni * 16 + (lane & 15)) * 128 + ko);
#pragma unroll
    for (int mi = 0; mi < 2; mi++)
#pragma unroll
      for (int ni = 0; ni < 8; ni++) acc[mi][ni] = MFMA(af[mi], bfr[ni], acc[mi][ni]);
  }
#pragma unroll
  for (int mi = 0; mi < 2; mi++)
#pragma unroll
    for (int r = 0; r < 4; r++) {
      float qd = __expf(-s * (float)(mm0 + mi * 16 + (lane >> 4) * 4 + r + 1));
#pragma unroll
      for (int ni = 0; ni < 8; ni++) acc[mi][ni][r] *= qd;
    }
  // intra-block: masked quadratic attention, 64-wide t-chunks
  int nchunk = 2 * (hf + 1);
  for (int tc = 0; tc < nchunk; ++tc) {
    __syncthreads();
    {  // stage K chunk rows [t][d]
      int t2 = tid >> 2, c = (tid & 3) * 32;
      const unsigned short* kp = kk + ((size_t)bh * 4096 + blk * 256 + tc * 64 + t2) * 128 + c;
#pragma unroll
      for (int g = 0; g < 4; ++g) *(short8*)&k_sh[t2][c + g * 8] = *(const short8*)(kp + g * 8);
    }
    {  // stage V^T chunk [e][t]
      int t2 = tid & 63, e0 = (tid >> 6) * 32;
      const unsigned short* vp = vv + ((size_t)bh * 4096 + blk * 256 + tc * 64 + t2) * 128 + e0;
#pragma unroll
      for (int g = 0; g < 4; ++g) {
        short8 v8 = *(const short8*)(vp + g * 8);
#pragma unroll
        for (int j = 0; j < 8; ++j) vT_sh[e0 + g * 8 + j][t2] = (unsigned short)v8[j];
      }
    }
    __syncthreads();
    if (tc * 64 <= mm0 + 31) {
      f32x4 sa[2][4];
#pragma unroll
      for (int m = 0; m < 2; m++)
#pragma unroll
        for (int n = 0; n < 4; n++) sa[m][n] = (f32x4)0.f;
#pragma unroll
      for (int kx = 0; kx < 128; kx += 32) {
        int ko = kx + (lane >> 4) * 8;
        short8 af[2], bfr[4];
#pragma unroll
        for (int mi = 0; mi < 2; mi++)
          af[mi] = *(const short8*)(qb + (size_t)(mm0 + mi * 16 + (lane & 15)) * 128 + ko);
#pragma unroll
        for (int ni = 0; ni < 4; ni++) bfr[ni] = *(const short8*)&k_sh[ni * 16 + (lane & 15)][ko];
#pragma unroll
        for (int mi = 0; mi < 2; mi++)
#pragma unroll
          for (int ni = 0; ni < 4; ni++) sa[mi][ni] = MFMA(af[mi], bfr[ni], sa[mi][ni]);
      }
      // mask * decay, to bf16, into per-wave S tile
#pragma unroll
      for (int mi = 0; mi < 2; mi++)
#pragma unroll
        for (int ni = 0; ni < 4; ni++)
#pragma unroll
          for (int r = 0; r < 4; r++) {
            int mm = mm0 + mi * 16 + (lane >> 4) * 4 + r;
            int ttg = tc * 64 + ni * 16 + (lane & 15);
            int diff = mm - ttg;
            float val = (diff >= 0) ? sa[mi][ni][r] * __expf(-s * (float)diff) : 0.f;
            s_sh[w][mi * 16 + (lane >> 4) * 4 + r][ni * 16 + (lane & 15)] = f2b(val);
          }
      // O += S @ V
#pragma unroll
      for (int k2 = 0; k2 < 64; k2 += 32) {
        int ko2 = k2 + (lane >> 4) * 8;
        short8 a2[2];
#pragma unroll
        for (int mi = 0; mi < 2; mi++)
          a2[mi] = *(const short8*)&s_sh[w][mi * 16 + (lane & 15)][ko2];
#pragma unroll
        for (int ni = 0; ni < 8; ni++) {
          short8 b2 = *(const short8*)&vT_sh[ni * 16 + (lane & 15)][ko2];
#pragma unroll
          for (int mi = 0; mi < 2; mi++) acc[mi][ni] = MFMA(a2[mi], b2, acc[mi][ni]);
        }
      }
    }
  }
  int b = bh >> 4, h = bh & 15;
#pragma unroll
  for (int mi = 0; mi < 2; mi++)
#pragma unroll
    for (int r = 0; r < 4; r++) {
      int mm = mm0 + mi * 16 + (lane >> 4) * 4 + r;
      size_t rowp = ((size_t)b * 4096 + blk * 256 + mm) * 2048 + h * 128;
#pragma unroll
      for (int ni = 0; ni < 8; ni++) attn[rowp + ni * 16 + (lane & 15)] = f2b(acc[mi][ni][r]);
    }
}

// ---------------- RMSNorm + gate ----------------
__global__ __launch_bounds__(256) void k_norm(const unsigned short* __restrict__ attn,
                                              const unsigned short* __restrict__ gate,
                                              const float* __restrict__ nw,
                                              unsigned short* __restrict__ y) {
  int row = blockIdx.x;  // 8192
  int tid = threadIdx.x, w = tid >> 6, lane = tid & 63;
  const unsigned short* ap = attn + (size_t)row * 2048 + tid * 8;
  const unsigned short* gp = gate + (size_t)row * 2048 + tid * 8;
  short8 a8 = *(const short8*)ap;
  float vals[8];
  float ss = 0.f;
#pragma unroll
  for (int j = 0; j < 8; ++j) {
    vals[j] = b2f((unsigned short)a8[j]);
    ss += vals[j] * vals[j];
  }
#pragma unroll
  for (int off = 32; off > 0; off >>= 1) ss += __shfl_down(ss, off, 64);
  __shared__ float red[4];
  if (lane == 0) red[w] = ss;
  __syncthreads();
  float tot = red[0] + red[1] + red[2] + red[3];
  float rms = rsqrtf(tot * (1.f / 2048.f) + 1.1920929e-07f);
  short8 g8 = *(const short8*)gp;
  short8 o;
#pragma unroll
  for (int j = 0; j < 8; ++j)
    o[j] = (short)f2b(vals[j] * rms * nw[tid * 8 + j] * b2f((unsigned short)g8[j]));
  *(short8*)(y + (size_t)row * 2048 + tid * 8) = o;
}

extern "C" void kernel_launch(void* const* d_in, const int* in_sizes, int n_in, void* d_out,
                              int out_size, void* d_ws, size_t ws_size, hipStream_t stream) {
  const float* x = (const float*)d_in[0];
  const float* slope = (const float*)d_in[1];
  const float* Wqkv = (const float*)d_in[2];
  const float* Wg = (const float*)d_in[3];
  const float* nw = (const float*)d_in[4];
  const float* Wo = (const float*)d_in[5];
  float* out = (float*)d_out;

  unsigned short* q = (unsigned short*)d_ws;               // 16,777,216 elems
  unsigned short* k = q + 16777216;                        // 16,777,216
  unsigned short* v = k + 16777216;                        // 16,777,216
  unsigned short* gate = v + 16777216;                     // 16,777,216
  unsigned short* xb = gate + 16777216;                    // 16,777,216
  unsigned short* wqkvb = xb + 16777216;                   // 12,582,912
  unsigned short* wgb = wqkvb + 12582912;                  // 4,194,304
  unsigned short* wob = wgb + 4194304;                     // 4,194,304
  unsigned short* kvT = wob + 4194304;                     // 8,388,608
  unsigned short* attn = wqkvb;  // alias: wqkvb+wgb dead after GEMM1 (exactly 16,777,216)
  unsigned short* y = xb;        // alias: xb dead after GEMM1

  k_f2b4<<<36864, 256, 0, stream>>>(x, Wqkv, Wg, Wo, xb);  // xb..wob contiguous

  k_gemm<0><<<1024, 512, 0, stream>>>(xb, wqkvb, wgb, q, k, v, gate, nullptr);
  k_kvblk<<<512, 256, 0, stream>>>(k, v, slope, kvT);
  k_scan<<<2048, 256, 0, stream>>>(kvT, slope);
  k_attn<<<1024, 256, 0, stream>>>(q, k, v, kvT, slope, attn);
  k_norm<<<8192, 256, 0, stream>>>(attn, gate, nw, y);
  k_gemm<1><<<256, 512, 0, stream>>>(y, wob, nullptr, nullptr, nullptr, nullptr, nullptr, out);
}

// Round 16
// 449.017 us; speedup vs baseline: 1.0731x; 1.0464x over previous
//
#include <hip/hip_runtime.h>
#include <stdint.h>

typedef __attribute__((ext_vector_type(8))) short short8;
typedef __attribute__((ext_vector_type(4))) float f32x4;

#define DEV static __device__ __forceinline__

DEV float b2f(unsigned short u) {
  unsigned x = ((unsigned)u) << 16;
  return __builtin_bit_cast(float, x);
}
DEV unsigned short f2b(float f) {
  unsigned x = __builtin_bit_cast(unsigned, f);
  return (unsigned short)((x + 0x7fffu + ((x >> 16) & 1u)) >> 16);
}
DEV void gload16(const unsigned short* g, unsigned short* l) {
  __builtin_amdgcn_global_load_lds((const __attribute__((address_space(1))) void*)g,
                                   (__attribute__((address_space(3))) void*)l, 16, 0, 0);
}
#define MFMA(a, b, c) __builtin_amdgcn_mfma_f32_16x16x32_bf16(a, b, c, 0, 0, 0)
#define BARRIER                          \
  asm volatile("" ::: "memory");         \
  __builtin_amdgcn_s_barrier();          \
  asm volatile("" ::: "memory")

// ---------------- fused fp32 -> bf16 convert (x, Wqkv, Wg, Wo -> one contiguous dst) ----
__global__ __launch_bounds__(256) void k_f2b4(const float* __restrict__ x,
                                              const float* __restrict__ wqkv,
                                              const float* __restrict__ wg,
                                              const float* __restrict__ wo,
                                              unsigned short* __restrict__ dst) {
  long gi = ((long)blockIdx.x * 256 + threadIdx.x) * 4;  // combined elem index
  const float* src;
  long off;
  if (gi < 16777216L) { src = x; off = gi; }
  else if (gi < 29360128L) { src = wqkv; off = gi - 16777216L; }
  else if (gi < 33554432L) { src = wg; off = gi - 29360128L; }
  else { src = wo; off = gi - 33554432L; }
  float4 f = *(const float4*)(src + off);
  ushort4 o;
  o.x = f2b(f.x); o.y = f2b(f.y); o.z = f2b(f.z); o.w = f2b(f.w);
  *(ushort4*)(dst + gi) = o;
}

// ---------------- 256x256-tile 8-wave 2-phase bf16 GEMM (R9 loop, best measured) --------
// LDS slots per K-tile (BK=64): 0 = A rows 0..127, 1 = B rows 0..127, 2 = A rows 128..255,
// 3 = B rows 128..255. Choreography:
//   P0(T): ds-read bfr<-B-slot(T) + af<-s0(T); stage s0,s1,s3(T+1); MFMA rows0-127;
//          vmcnt(6) [s2(T) done]; barrier.
//   P1(T): ds-read af<-s2(T); stage s2(T+1); MFMA rows128-255; vmcnt(2) [s013(T+1) done];
//          barrier.
// Hoisted addressing; NO explicit lgkmcnt before MFMA (compiler's fine interleave wins).
// MODE 0 epilogue: vmcnt(0)+barrier, activations in regs -> bf16 -> XOR-swizzled LDS
// repack -> coalesced 16B stores. Measured: 265us, MfmaUtil 48, conflicts 0 (R9).
// XCD chunking: tm = xcd*4+(sub&3), tn = sub>>2.
template <int MODE>
__global__ __launch_bounds__(512, 2) void k_gemm(
    const unsigned short* __restrict__ A, const unsigned short* __restrict__ B0,
    const unsigned short* __restrict__ B1,
    unsigned short* __restrict__ o_q, unsigned short* __restrict__ o_k,
    unsigned short* __restrict__ o_v, unsigned short* __restrict__ o_g,
    float* __restrict__ o_f) {
  const int K = 2048, NT = 32;
  __shared__ unsigned short sm[65536];  // 128 KiB: 2 bufs x 4 slots x 8192 shorts
  int tid = threadIdx.x, w = tid >> 6, lane = tid & 63;
  int wm = w >> 2, wn = w & 3;
  int l15 = lane & 15, l4 = lane >> 4;
  int xcd = blockIdx.x & 7, sub = blockIdx.x >> 3;
  int tm = xcd * 4 + (sub & 3), tn = sub >> 2;
  int brow = tm << 8, bcol = tn << 8;
  const unsigned short* Ab = A + (size_t)brow * K;
  const unsigned short* Bb = (MODE == 1 || bcol < 6144) ? (B0 + (size_t)bcol * K)
                                                        : (B1 + (size_t)(bcol - 6144) * K);
  f32x4 acc[8][4];
#pragma unroll
  for (int m = 0; m < 8; m++)
#pragma unroll
    for (int n = 0; n < 4; n++) acc[m][n] = (f32x4)0.f;

  // ---- precomputed LDS read byte-offsets (relative to sm, buffer 0) ----
  int rdA[4][2], rdB[4][2];
  const int bslot = (wn >> 1) ? 3 : 1;
  const int bposb = (wn & 1) * 64;
#pragma unroll
  for (int fi = 0; fi < 4; ++fi) {
#pragma unroll
    for (int ks = 0; ks < 2; ++ks) {
      int posA = wm * 64 + fi * 16 + l15;
      rdA[fi][ks] = posA * 128 + (((ks * 4 + l4) ^ (posA & 7)) << 4);
      int posB = bposb + fi * 16 + l15;
      rdB[fi][ks] = bslot * 16384 + posB * 128 + (((ks * 4 + l4) ^ (posB & 7)) << 4);
    }
  }
  // ---- persistent global stage pointers (slot s, chunk i) + LDS dest offsets ----
  const unsigned short* gP[4][2];
  int dL[4][2];
#pragma unroll
  for (int s = 0; s < 4; ++s) {
#pragma unroll
    for (int i = 0; i < 2; ++i) {
      int c = i * 512 + tid;
      int pos = c >> 3, pb = c & 7;
      const unsigned short* gb = (s & 1) ? Bb : Ab;
      int ro = (s >> 1) << 7;
      gP[s][i] = gb + (size_t)(ro + pos) * K + ((pb ^ (pos & 7)) << 3);
      dL[s][i] = s * 16384 + c * 16;  // bytes, buffer 0
    }
  }

  auto stage = [&](int s, int tgl) {  // issue slot s into buffer-parity tgl (bytes<<16)
#pragma unroll
    for (int i = 0; i < 2; ++i) {
      gload16(gP[s][i], (unsigned short*)((char*)sm + (dL[s][i] + tgl)));
      gP[s][i] += 64;  // advance one K-tile (128 B)
    }
  };

  // prologue: stage tile0 {s0,s1,s3,s2}; wait s0,s1,s3
  stage(0, 0); stage(1, 0); stage(3, 0); stage(2, 0);
  asm volatile("s_waitcnt vmcnt(2)" ::: "memory");
  BARRIER;

  for (int T = 0; T < NT; ++T) {
    const char* smb = (const char*)sm + ((T & 1) << 16);
    int tglS = ((T + 1) & 1) << 16;
    short8 af[4][2], bfr[4][2];
    // ---- P0: C rows 0..127 ----
#pragma unroll
    for (int nj = 0; nj < 4; ++nj)
#pragma unroll
      for (int ks = 0; ks < 2; ++ks) bfr[nj][ks] = *(const short8*)(smb + rdB[nj][ks]);
#pragma unroll
    for (int fi = 0; fi < 4; ++fi)
#pragma unroll
      for (int ks = 0; ks < 2; ++ks) af[fi][ks] = *(const short8*)(smb + rdA[fi][ks]);
    stage(0, tglS); stage(1, tglS); stage(3, tglS);
    __builtin_amdgcn_s_setprio(1);
#pragma unroll
    for (int mi = 0; mi < 4; ++mi)
#pragma unroll
      for (int nj = 0; nj < 4; ++nj)
#pragma unroll
        for (int ks = 0; ks < 2; ++ks) acc[mi][nj] = MFMA(af[mi][ks], bfr[nj][ks], acc[mi][nj]);
    __builtin_amdgcn_s_setprio(0);
    asm volatile("s_waitcnt vmcnt(6)" ::: "memory");  // s2(T) done
    BARRIER;
    // ---- P1: C rows 128..255 ----
#pragma unroll
    for (int fi = 0; fi < 4; ++fi)
#pragma unroll
      for (int ks = 0; ks < 2; ++ks)
        af[fi][ks] = *(const short8*)(smb + (rdA[fi][ks] + 32768));  // slot2
    stage(2, tglS);
    __builtin_amdgcn_s_setprio(1);
#pragma unroll
    for (int mi = 0; mi < 4; ++mi)
#pragma unroll
      for (int nj = 0; nj < 4; ++nj)
#pragma unroll
        for (int ks = 0; ks < 2; ++ks)
          acc[4 + mi][nj] = MFMA(af[mi][ks], bfr[nj][ks], acc[4 + mi][nj]);
    __builtin_amdgcn_s_setprio(0);
    asm volatile("s_waitcnt vmcnt(2)" ::: "memory");  // s0,s1,s3(T+1) done
    BARRIER;
  }
  asm volatile("s_waitcnt vmcnt(0)" ::: "memory");  // drain tail DMA before reusing sm
  BARRIER;

  if (MODE == 0) {
    // ---- repack epilogue: activation in regs -> bf16 -> swizzled LDS [256][256] ----
#pragma unroll
    for (int mf = 0; mf < 8; ++mf) {
      int rowb = (mf >> 2) * 128 + wm * 64 + (mf & 3) * 16 + l4 * 4;
#pragma unroll
      for (int ni = 0; ni < 4; ++ni) {
        int cx = wn * 64 + ((ni ^ l4) << 4) + l15;  // col XOR l4<<4 (conflict-free)
        int colg = bcol + wn * 64 + ni * 16 + l15;
#pragma unroll
        for (int r = 0; r < 4; ++r) {
          float v = acc[mf][ni][r];
          float a = (colg < 6144) ? v / (1.f + __expf(-v))    // silu
                                  : 1.f / (1.f + __expf(-v)); // sigmoid
          sm[(rowb + r) * 256 + cx] = f2b(a);
        }
      }
    }
    BARRIER;
    // ---- coalesced readout: 16 iters x (16 rows x 32 16B-chunks) ----
    int rl0 = tid >> 5;        // 0..15
    int ch = (tid & 31) * 8;   // chunk col base
    int cg = bcol + ch;        // global col (block-uniform q/k/v vs gate)
    unsigned short* qkvb = nullptr;
    size_t hbase = 0;
    int off = 0;
    const bool isq = (cg < 6144);
    if (isq) {
      int hh = cg / 384, dd = cg - hh * 384;
      int sel = dd >> 7;
      off = dd & 127;
      qkvb = (sel == 0) ? o_q : (sel == 1) ? o_k : o_v;
      hbase = (size_t)hh * 4096;
    }
#pragma unroll
    for (int it = 0; it < 16; ++it) {
      int rl = it * 16 + rl0;
      int cx = ch ^ (((rl >> 2) & 3) << 4);
      short8 v8 = *(const short8*)(sm + rl * 256 + cx);
      int row = brow + rl;
      if (isq) {
        int b = row >> 12, t = row & 4095;
        *(short8*)(qkvb + ((size_t)b * 65536 + hbase + t) * 128 + off) = v8;
      } else {
        *(short8*)(o_g + (size_t)row * 2048 + (cg - 6144)) = v8;
      }
    }
  } else {
#pragma unroll
    for (int mf = 0; mf < 8; ++mf)
#pragma unroll
      for (int r = 0; r < 4; ++r) {
        int row = brow + (mf >> 2) * 128 + wm * 64 + (mf & 3) * 16 + l4 * 4 + r;
#pragma unroll
        for (int ni = 0; ni < 4; ++ni) {
          int col = bcol + wn * 64 + ni * 16 + l15;
          o_f[(size_t)row * 2048 + col] = acc[mf][ni][r];
        }
      }
  }
}

// ---------------- per-block KV contribution: kvT[e][d] = sum_t V[t][e] * K[t][d]*kd[t] ----------------
__global__ __launch_bounds__(256) void k_kvblk(const unsigned short* __restrict__ kk,
                                               const unsigned short* __restrict__ vv,
                                               const float* __restrict__ slope,
                                               unsigned short* __restrict__ kvT) {
  int gid = blockIdx.x;  // 512 = bh*16 + blk
  int bh = gid >> 4, blk = gid & 15;
  float s = slope[bh & 15];
  __shared__ unsigned short kT[128][72];
  __shared__ unsigned short vT[128][72];
  int tid = threadIdx.x, w = tid >> 6, lane = tid & 63;
  int wrow = (w >> 1) * 64, wcol = (w & 1) * 64;
  f32x4 acc[4][4];
#pragma unroll
  for (int m = 0; m < 4; m++)
#pragma unroll
    for (int n = 0; n < 4; n++) acc[m][n] = (f32x4)0.f;
  const unsigned short* kb = kk + ((size_t)bh * 4096 + blk * 256) * 128;
  const unsigned short* vb = vv + ((size_t)bh * 4096 + blk * 256) * 128;
  int tt = tid & 63, c0 = (tid >> 6) * 32;
  for (int tc = 0; tc < 4; ++tc) {
    __syncthreads();
    int tg = tc * 64 + tt;
    float kd = __expf(-s * (float)(255 - tg));
#pragma unroll
    for (int g = 0; g < 4; ++g) {
      int c = c0 + g * 8;
      short8 k8 = *(const short8*)(kb + (size_t)tg * 128 + c);
      short8 v8 = *(const short8*)(vb + (size_t)tg * 128 + c);
#pragma unroll
      for (int j = 0; j < 8; ++j) {
        kT[c + j][tt] = f2b(b2f((unsigned short)k8[j]) * kd);
        vT[c + j][tt] = (unsigned short)v8[j];
      }
    }
    __syncthreads();
#pragma unroll
    for (int kx = 0; kx < 64; kx += 32) {
      int ko = kx + (lane >> 4) * 8;
      short8 af[4], bfr[4];
#pragma unroll
      for (int m = 0; m < 4; m++) af[m] = *(const short8*)&vT[wrow + m * 16 + (lane & 15)][ko];
#pragma unroll
      for (int n = 0; n < 4; n++) bfr[n] = *(const short8*)&kT[wcol + n * 16 + (lane & 15)][ko];
#pragma unroll
      for (int m = 0; m < 4; m++)
#pragma unroll
        for (int n = 0; n < 4; n++) acc[m][n] = MFMA(af[m], bfr[n], acc[m][n]);
    }
  }
  unsigned short* op = kvT + (size_t)gid * 16384;
#pragma unroll
  for (int m = 0; m < 4; m++)
#pragma unroll
    for (int r = 0; r < 4; r++) {
      int e = wrow + m * 16 + (lane >> 4) * 4 + r;
#pragma unroll
      for (int n = 0; n < 4; n++) {
        int d = wcol + n * 16 + (lane & 15);
        op[e * 128 + d] = f2b(acc[m][n][r]);
      }
    }
}

// ---------------- decay prefix scan over blocks (in place: kvT[i] := state before block i) ----------------
__global__ void k_scan(unsigned short* kvT, const float* __restrict__ slope) {
  int gid = blockIdx.x;  // 2048
  int bh = gid >> 6;
  int eo = (gid & 63) * 256 + threadIdx.x;  // 0..16383
  float s = slope[bh & 15];
  float bd = __expf(-s * 256.f);
  float st = 0.f;
  size_t base = (size_t)bh * 16 * 16384 + eo;
#pragma unroll
  for (int i = 0; i < 16; ++i) {
    unsigned short c = kvT[base + (size_t)i * 16384];
    kvT[base + (size_t)i * 16384] = f2b(st);
    st = bd * st + b2f(c);
  }
}

// ---------------- per-block attention output ----------------
// LDS pool aliasing: k_sh(17408B) + vT_sh(18432B) + s_sh(18432B) = 54272B during compute;
// after final barrier the pool is reused as a [128][128] bf16 output repack tile (32768B).
// Write: logical col (ni*16+l15) of row stored at col ^ (l4<<4), l4 = (row>>2)&3 -- banks
// 2-way (free). Read: logical 8-short chunk c of row rl is at (c*8) ^ (((rl>>2)&3)<<4).
// 16 consecutive lanes stream one contiguous 256B head-row -> 8 coalesced 16B stores/thread.
__global__ __launch_bounds__(256) void k_attn(const unsigned short* __restrict__ q,
                                              const unsigned short* __restrict__ kk,
                                              const unsigned short* __restrict__ vv,
                                              const unsigned short* __restrict__ kvT,
                                              const float* __restrict__ slope,
                                              unsigned short* __restrict__ attn) {
  int gid = blockIdx.x;  // 1024 = (bh*16 + blk)*2 + hf
  int hf = gid & 1, blk = (gid >> 1) & 15, bh = gid >> 5;
  float s = slope[bh & 15];
  __shared__ char pool[54272] __attribute__((aligned(16)));
  auto k_sh = (unsigned short(*)[136])pool;
  auto vT_sh = (unsigned short(*)[72])(pool + 17408);
  auto s_sh = (unsigned short(*)[32][72])(pool + 35840);
  unsigned short* osm = (unsigned short*)pool;  // repack tile, after final barrier
  int tid = threadIdx.x, w = tid >> 6, lane = tid & 63;
  int mm0 = hf * 128 + w * 32;  // wave's first within-block row
  const unsigned short* qb = q + ((size_t)bh * 4096 + blk * 256) * 128;
  const unsigned short* kvb = kvT + (size_t)(bh * 16 + blk) * 16384;
  f32x4 acc[2][8];
#pragma unroll
  for (int m = 0; m < 2; m++)
#pragma unroll
    for (int n = 0; n < 8; n++) acc[m][n] = (f32x4)0.f;
  // inter-block: (q) @ KV_pre   (row-scale by q_decay afterwards)
#pragma unroll
  for (int kx = 0; kx < 128; kx += 32) {
    int ko = kx + (lane >> 4) * 8;
    short8 af[2], bfr[8];
#pragma unroll
    for (int mi = 0; mi < 2; mi++)
      af[mi] = *(const short8*)(qb + (size_t)(mm0 + mi * 16 + (lane & 15)) * 128 + ko);
#pragma unroll
    for (int ni = 0; ni < 8; ni++)
      bfr[ni] = *(const short8*)(kvb + (size_t)(ni * 16 + (lane & 15)) * 128 + ko);
#pragma unroll
    for (int mi = 0; mi < 2; mi++)
#pragma unroll
      for (int ni = 0; ni < 8; ni++) acc[mi][ni] = MFMA(af[mi], bfr[ni], acc[mi][ni]);
  }
#pragma unroll
  for (int mi = 0; mi < 2; mi++)
#pragma unroll
    for (int r = 0; r < 4; r++) {
      float qd = __expf(-s * (float)(mm0 + mi * 16 + (lane >> 4) * 4 + r + 1));
#pragma unroll
      for (int ni = 0; ni < 8; ni++) acc[mi][ni][r] *= qd;
    }
  // intra-block: masked quadratic attention, 64-wide t-chunks
  int nchunk = 2 * (hf + 1);
  for (int tc = 0; tc < nchunk; ++tc) {
    __syncthreads();
    {  // stage K chunk rows [t][d]
      int t2 = tid >> 2, c = (tid & 3) * 32;
      const unsigned short* kp = kk + ((size_t)bh * 4096 + blk * 256 + tc * 64 + t2) * 128 + c;
#pragma unroll
      for (int g = 0; g < 4; ++g) *(short8*)&k_sh[t2][c + g * 8] = *(const short8*)(kp + g * 8);
    }
    {  // stage V^T chunk [e][t]
      int t2 = tid & 63, e0 = (tid >> 6) * 32;
      const unsigned short* vp = vv + ((size_t)bh * 4096 + blk * 256 + tc * 64 + t2) * 128 + e0;
#pragma unroll
      for (int g = 0; g < 4; ++g) {
        short8 v8 = *(const short8*)(vp + g * 8);
#pragma unroll
        for (int j = 0; j < 8; ++j) vT_sh[e0 + g * 8 + j][t2] = (unsigned short)v8[j];
      }
    }
    __syncthreads();
    if (tc * 64 <= mm0 + 31) {
      f32x4 sa[2][4];
#pragma unroll
      for (int m = 0; m < 2; m++)
#pragma unroll
        for (int n = 0; n < 4; n++) sa[m][n] = (f32x4)0.f;
#pragma unroll
      for (int kx = 0; kx < 128; kx += 32) {
        int ko = kx + (lane >> 4) * 8;
        short8 af[2], bfr[4];
#pragma unroll
        for (int mi = 0; mi < 2; mi++)
          af[mi] = *(const short8*)(qb + (size_t)(mm0 + mi * 16 + (lane & 15)) * 128 + ko);
#pragma unroll
        for (int ni = 0; ni < 4; ni++) bfr[ni] = *(const short8*)&k_sh[ni * 16 + (lane & 15)][ko];
#pragma unroll
        for (int mi = 0; mi < 2; mi++)
#pragma unroll
          for (int ni = 0; ni < 4; ni++) sa[mi][ni] = MFMA(af[mi], bfr[ni], sa[mi][ni]);
      }
      // mask * decay, to bf16, into per-wave S tile
#pragma unroll
      for (int mi = 0; mi < 2; mi++)
#pragma unroll
        for (int ni = 0; ni < 4; ni++)
#pragma unroll
          for (int r = 0; r < 4; r++) {
            int mm = mm0 + mi * 16 + (lane >> 4) * 4 + r;
            int ttg = tc * 64 + ni * 16 + (lane & 15);
            int diff = mm - ttg;
            float val = (diff >= 0) ? sa[mi][ni][r] * __expf(-s * (float)diff) : 0.f;
            s_sh[w][mi * 16 + (lane >> 4) * 4 + r][ni * 16 + (lane & 15)] = f2b(val);
          }
      // O += S @ V
#pragma unroll
      for (int k2 = 0; k2 < 64; k2 += 32) {
        int ko2 = k2 + (lane >> 4) * 8;
        short8 a2[2];
#pragma unroll
        for (int mi = 0; mi < 2; mi++)
          a2[mi] = *(const short8*)&s_sh[w][mi * 16 + (lane & 15)][ko2];
#pragma unroll
        for (int ni = 0; ni < 8; ni++) {
          short8 b2 = *(const short8*)&vT_sh[ni * 16 + (lane & 15)][ko2];
#pragma unroll
          for (int mi = 0; mi < 2; mi++) acc[mi][ni] = MFMA(a2[mi], b2, acc[mi][ni]);
        }
      }
    }
  }
  // ---- output repack: acc -> swizzled LDS [128][128] -> coalesced 16B stores ----
  BARRIER;  // all s_sh/vT_sh reads done before pool reuse
  int l15 = lane & 15, l4 = lane >> 4;
#pragma unroll
  for (int mi = 0; mi < 2; mi++)
#pragma unroll
    for (int ni = 0; ni < 8; ni++) {
      int cx = ((ni * 16 + l15) ^ (l4 << 4));
      int rowb = w * 32 + mi * 16 + l4 * 4;
#pragma unroll
      for (int r = 0; r < 4; r++) osm[(rowb + r) * 128 + cx] = f2b(acc[mi][ni][r]);
    }
  BARRIER;
  {
    int b = bh >> 4, h = bh & 15;
    int rl0 = tid >> 4;       // 0..15
    int c = tid & 15;         // 8-short chunk index within the 128-col head row
#pragma unroll
    for (int it = 0; it < 8; ++it) {
      int rl = it * 16 + rl0;
      int e = (c * 8) ^ (((rl >> 2) & 3) << 4);  // inverse of write swizzle
      short8 v8 = *(const short8*)(osm + rl * 128 + e);
      size_t rowp = ((size_t)b * 4096 + blk * 256 + hf * 128 + rl) * 2048 + h * 128 + c * 8;
      *(short8*)(attn + rowp) = v8;
    }
  }
}

// ---------------- RMSNorm + gate ----------------
__global__ __launch_bounds__(256) void k_norm(const unsigned short* __restrict__ attn,
                                              const unsigned short* __restrict__ gate,
                                              const float* __restrict__ nw,
                                              unsigned short* __restrict__ y) {
  int row = blockIdx.x;  // 8192
  int tid = threadIdx.x, w = tid >> 6, lane = tid & 63;
  const unsigned short* ap = attn + (size_t)row * 2048 + tid * 8;
  const unsigned short* gp = gate + (size_t)row * 2048 + tid * 8;
  short8 a8 = *(const short8*)ap;
  float vals[8];
  float ss = 0.f;
#pragma unroll
  for (int j = 0; j < 8; ++j) {
    vals[j] = b2f((unsigned short)a8[j]);
    ss += vals[j] * vals[j];
  }
#pragma unroll
  for (int off = 32; off > 0; off >>= 1) ss += __shfl_down(ss, off, 64);
  __shared__ float red[4];
  if (lane == 0) red[w] = ss;
  __syncthreads();
  float tot = red[0] + red[1] + red[2] + red[3];
  float rms = rsqrtf(tot * (1.f / 2048.f) + 1.1920929e-07f);
  short8 g8 = *(const short8*)gp;
  short8 o;
#pragma unroll
  for (int j = 0; j < 8; ++j)
    o[j] = (short)f2b(vals[j] * rms * nw[tid * 8 + j] * b2f((unsigned short)g8[j]));
  *(short8*)(y + (size_t)row * 2048 + tid * 8) = o;
}

extern "C" void kernel_launch(void* const* d_in, const int* in_sizes, int n_in, void* d_out,
                              int out_size, void* d_ws, size_t ws_size, hipStream_t stream) {
  const float* x = (const float*)d_in[0];
  const float* slope = (const float*)d_in[1];
  const float* Wqkv = (const float*)d_in[2];
  const float* Wg = (const float*)d_in[3];
  const float* nw = (const float*)d_in[4];
  const float* Wo = (const float*)d_in[5];
  float* out = (float*)d_out;

  unsigned short* q = (unsigned short*)d_ws;               // 16,777,216 elems
  unsigned short* k = q + 16777216;                        // 16,777,216
  unsigned short* v = k + 16777216;                        // 16,777,216
  unsigned short* gate = v + 16777216;                     // 16,777,216
  unsigned short* xb = gate + 16777216;                    // 16,777,216
  unsigned short* wqkvb = xb + 16777216;                   // 12,582,912
  unsigned short* wgb = wqkvb + 12582912;                  // 4,194,304
  unsigned short* wob = wgb + 4194304;                     // 4,194,304
  unsigned short* kvT = wob + 4194304;                     // 8,388,608
  unsigned short* attn = wqkvb;  // alias: wqkvb+wgb dead after GEMM1 (exactly 16,777,216)
  unsigned short* y = xb;        // alias: xb dead after GEMM1

  k_f2b4<<<36864, 256, 0, stream>>>(x, Wqkv, Wg, Wo, xb);  // xb..wob contiguous

  k_gemm<0><<<1024, 512, 0, stream>>>(xb, wqkvb, wgb, q, k, v, gate, nullptr);
  k_kvblk<<<512, 256, 0, stream>>>(k, v, slope, kvT);
  k_scan<<<2048, 256, 0, stream>>>(kvT, slope);
  k_attn<<<1024, 256, 0, stream>>>(q, k, v, kvT, slope, attn);
  k_norm<<<8192, 256, 0, stream>>>(attn, gate, nw, y);
  k_gemm<1><<<256, 512, 0, stream>>>(y, wob, nullptr, nullptr, nullptr, nullptr, nullptr, out);
}

// Round 17
// 443.235 us; speedup vs baseline: 1.0871x; 1.0130x over previous
//
#include <hip/hip_runtime.h>
#include <stdint.h>

typedef __attribute__((ext_vector_type(8))) short short8;
typedef __attribute__((ext_vector_type(4))) float f32x4;

#define DEV static __device__ __forceinline__

DEV float b2f(unsigned short u) {
  unsigned x = ((unsigned)u) << 16;
  return __builtin_bit_cast(float, x);
}
DEV unsigned short f2b(float f) {
  unsigned x = __builtin_bit_cast(unsigned, f);
  return (unsigned short)((x + 0x7fffu + ((x >> 16) & 1u)) >> 16);
}
DEV void gload16(const unsigned short* g, unsigned short* l) {
  __builtin_amdgcn_global_load_lds((const __attribute__((address_space(1))) void*)g,
                                   (__attribute__((address_space(3))) void*)l, 16, 0, 0);
}
#define MFMA(a, b, c) __builtin_amdgcn_mfma_f32_16x16x32_bf16(a, b, c, 0, 0, 0)
#define BARRIER                          \
  asm volatile("" ::: "memory");         \
  __builtin_amdgcn_s_barrier();          \
  asm volatile("" ::: "memory")

// ---------------- fused fp32 -> bf16 convert (x, Wqkv, Wg, Wo -> one contiguous dst) ----
__global__ __launch_bounds__(256) void k_f2b4(const float* __restrict__ x,
                                              const float* __restrict__ wqkv,
                                              const float* __restrict__ wg,
                                              const float* __restrict__ wo,
                                              unsigned short* __restrict__ dst) {
  long gi = ((long)blockIdx.x * 256 + threadIdx.x) * 4;  // combined elem index
  const float* src;
  long off;
  if (gi < 16777216L) { src = x; off = gi; }
  else if (gi < 29360128L) { src = wqkv; off = gi - 16777216L; }
  else if (gi < 33554432L) { src = wg; off = gi - 29360128L; }
  else { src = wo; off = gi - 33554432L; }
  float4 f = *(const float4*)(src + off);
  ushort4 o;
  o.x = f2b(f.x); o.y = f2b(f.y); o.z = f2b(f.z); o.w = f2b(f.w);
  *(ushort4*)(dst + gi) = o;
}

// ---------------- 256x256-tile 8-wave 2-phase bf16 GEMM (R9 loop, best measured) --------
// LDS slots per K-tile (BK=64): 0 = A rows 0..127, 1 = B rows 0..127, 2 = A rows 128..255,
// 3 = B rows 128..255. Choreography:
//   P0(T): ds-read bfr<-B-slot(T) + af<-s0(T); stage s0,s1,s3(T+1); MFMA rows0-127;
//          vmcnt(6) [s2(T) done]; barrier.
//   P1(T): ds-read af<-s2(T); stage s2(T+1); MFMA rows128-255; vmcnt(2) [s013(T+1) done];
//          barrier.
// Hoisted addressing; NO explicit lgkmcnt before MFMA (compiler's fine interleave wins).
// MODE 0 epilogue: vmcnt(0)+barrier, activations in regs -> bf16 -> XOR-swizzled LDS
// repack -> coalesced 16B stores. Measured: 265us, MfmaUtil 48, conflicts 0.
// XCD chunking: tm = xcd*4+(sub&3), tn = sub>>2.
template <int MODE>
__global__ __launch_bounds__(512, 2) void k_gemm(
    const unsigned short* __restrict__ A, const unsigned short* __restrict__ B0,
    const unsigned short* __restrict__ B1,
    unsigned short* __restrict__ o_q, unsigned short* __restrict__ o_k,
    unsigned short* __restrict__ o_v, unsigned short* __restrict__ o_g,
    float* __restrict__ o_f) {
  const int K = 2048, NT = 32;
  __shared__ unsigned short sm[65536];  // 128 KiB: 2 bufs x 4 slots x 8192 shorts
  int tid = threadIdx.x, w = tid >> 6, lane = tid & 63;
  int wm = w >> 2, wn = w & 3;
  int l15 = lane & 15, l4 = lane >> 4;
  int xcd = blockIdx.x & 7, sub = blockIdx.x >> 3;
  int tm = xcd * 4 + (sub & 3), tn = sub >> 2;
  int brow = tm << 8, bcol = tn << 8;
  const unsigned short* Ab = A + (size_t)brow * K;
  const unsigned short* Bb = (MODE == 1 || bcol < 6144) ? (B0 + (size_t)bcol * K)
                                                        : (B1 + (size_t)(bcol - 6144) * K);
  f32x4 acc[8][4];
#pragma unroll
  for (int m = 0; m < 8; m++)
#pragma unroll
    for (int n = 0; n < 4; n++) acc[m][n] = (f32x4)0.f;

  // ---- precomputed LDS read byte-offsets (relative to sm, buffer 0) ----
  int rdA[4][2], rdB[4][2];
  const int bslot = (wn >> 1) ? 3 : 1;
  const int bposb = (wn & 1) * 64;
#pragma unroll
  for (int fi = 0; fi < 4; ++fi) {
#pragma unroll
    for (int ks = 0; ks < 2; ++ks) {
      int posA = wm * 64 + fi * 16 + l15;
      rdA[fi][ks] = posA * 128 + (((ks * 4 + l4) ^ (posA & 7)) << 4);
      int posB = bposb + fi * 16 + l15;
      rdB[fi][ks] = bslot * 16384 + posB * 128 + (((ks * 4 + l4) ^ (posB & 7)) << 4);
    }
  }
  // ---- persistent global stage pointers (slot s, chunk i) + LDS dest offsets ----
  const unsigned short* gP[4][2];
  int dL[4][2];
#pragma unroll
  for (int s = 0; s < 4; ++s) {
#pragma unroll
    for (int i = 0; i < 2; ++i) {
      int c = i * 512 + tid;
      int pos = c >> 3, pb = c & 7;
      const unsigned short* gb = (s & 1) ? Bb : Ab;
      int ro = (s >> 1) << 7;
      gP[s][i] = gb + (size_t)(ro + pos) * K + ((pb ^ (pos & 7)) << 3);
      dL[s][i] = s * 16384 + c * 16;  // bytes, buffer 0
    }
  }

  auto stage = [&](int s, int tgl) {  // issue slot s into buffer-parity tgl (bytes<<16)
#pragma unroll
    for (int i = 0; i < 2; ++i) {
      gload16(gP[s][i], (unsigned short*)((char*)sm + (dL[s][i] + tgl)));
      gP[s][i] += 64;  // advance one K-tile (128 B)
    }
  };

  // prologue: stage tile0 {s0,s1,s3,s2}; wait s0,s1,s3
  stage(0, 0); stage(1, 0); stage(3, 0); stage(2, 0);
  asm volatile("s_waitcnt vmcnt(2)" ::: "memory");
  BARRIER;

  for (int T = 0; T < NT; ++T) {
    const char* smb = (const char*)sm + ((T & 1) << 16);
    int tglS = ((T + 1) & 1) << 16;
    short8 af[4][2], bfr[4][2];
    // ---- P0: C rows 0..127 ----
#pragma unroll
    for (int nj = 0; nj < 4; ++nj)
#pragma unroll
      for (int ks = 0; ks < 2; ++ks) bfr[nj][ks] = *(const short8*)(smb + rdB[nj][ks]);
#pragma unroll
    for (int fi = 0; fi < 4; ++fi)
#pragma unroll
      for (int ks = 0; ks < 2; ++ks) af[fi][ks] = *(const short8*)(smb + rdA[fi][ks]);
    stage(0, tglS); stage(1, tglS); stage(3, tglS);
    __builtin_amdgcn_s_setprio(1);
#pragma unroll
    for (int mi = 0; mi < 4; ++mi)
#pragma unroll
      for (int nj = 0; nj < 4; ++nj)
#pragma unroll
        for (int ks = 0; ks < 2; ++ks) acc[mi][nj] = MFMA(af[mi][ks], bfr[nj][ks], acc[mi][nj]);
    __builtin_amdgcn_s_setprio(0);
    asm volatile("s_waitcnt vmcnt(6)" ::: "memory");  // s2(T) done
    BARRIER;
    // ---- P1: C rows 128..255 ----
#pragma unroll
    for (int fi = 0; fi < 4; ++fi)
#pragma unroll
      for (int ks = 0; ks < 2; ++ks)
        af[fi][ks] = *(const short8*)(smb + (rdA[fi][ks] + 32768));  // slot2
    stage(2, tglS);
    __builtin_amdgcn_s_setprio(1);
#pragma unroll
    for (int mi = 0; mi < 4; ++mi)
#pragma unroll
      for (int nj = 0; nj < 4; ++nj)
#pragma unroll
        for (int ks = 0; ks < 2; ++ks)
          acc[4 + mi][nj] = MFMA(af[mi][ks], bfr[nj][ks], acc[4 + mi][nj]);
    __builtin_amdgcn_s_setprio(0);
    asm volatile("s_waitcnt vmcnt(2)" ::: "memory");  // s0,s1,s3(T+1) done
    BARRIER;
  }
  asm volatile("s_waitcnt vmcnt(0)" ::: "memory");  // drain tail DMA before reusing sm
  BARRIER;

  if (MODE == 0) {
    // ---- repack epilogue: activation in regs -> bf16 -> swizzled LDS [256][256] ----
#pragma unroll
    for (int mf = 0; mf < 8; ++mf) {
      int rowb = (mf >> 2) * 128 + wm * 64 + (mf & 3) * 16 + l4 * 4;
#pragma unroll
      for (int ni = 0; ni < 4; ++ni) {
        int cx = wn * 64 + ((ni ^ l4) << 4) + l15;  // col XOR l4<<4 (conflict-free)
        int colg = bcol + wn * 64 + ni * 16 + l15;
#pragma unroll
        for (int r = 0; r < 4; ++r) {
          float v = acc[mf][ni][r];
          float a = (colg < 6144) ? v / (1.f + __expf(-v))    // silu
                                  : 1.f / (1.f + __expf(-v)); // sigmoid
          sm[(rowb + r) * 256 + cx] = f2b(a);
        }
      }
    }
    BARRIER;
    // ---- coalesced readout: 16 iters x (16 rows x 32 16B-chunks) ----
    int rl0 = tid >> 5;        // 0..15
    int ch = (tid & 31) * 8;   // chunk col base
    int cg = bcol + ch;        // global col (block-uniform q/k/v vs gate)
    unsigned short* qkvb = nullptr;
    size_t hbase = 0;
    int off = 0;
    const bool isq = (cg < 6144);
    if (isq) {
      int hh = cg / 384, dd = cg - hh * 384;
      int sel = dd >> 7;
      off = dd & 127;
      qkvb = (sel == 0) ? o_q : (sel == 1) ? o_k : o_v;
      hbase = (size_t)hh * 4096;
    }
#pragma unroll
    for (int it = 0; it < 16; ++it) {
      int rl = it * 16 + rl0;
      int cx = ch ^ (((rl >> 2) & 3) << 4);
      short8 v8 = *(const short8*)(sm + rl * 256 + cx);
      int row = brow + rl;
      if (isq) {
        int b = row >> 12, t = row & 4095;
        *(short8*)(qkvb + ((size_t)b * 65536 + hbase + t) * 128 + off) = v8;
      } else {
        *(short8*)(o_g + (size_t)row * 2048 + (cg - 6144)) = v8;
      }
    }
  } else {
#pragma unroll
    for (int mf = 0; mf < 8; ++mf)
#pragma unroll
      for (int r = 0; r < 4; ++r) {
        int row = brow + (mf >> 2) * 128 + wm * 64 + (mf & 3) * 16 + l4 * 4 + r;
#pragma unroll
        for (int ni = 0; ni < 4; ++ni) {
          int col = bcol + wn * 64 + ni * 16 + l15;
          o_f[(size_t)row * 2048 + col] = acc[mf][ni][r];
        }
      }
  }
}

// ---------------- per-block KV contribution: kvT[e][d] = sum_t V[t][e] * K[t][d]*kd[t] ----------------
__global__ __launch_bounds__(256) void k_kvblk(const unsigned short* __restrict__ kk,
                                               const unsigned short* __restrict__ vv,
                                               const float* __restrict__ slope,
                                               unsigned short* __restrict__ kvT) {
  int gid = blockIdx.x;  // 512 = bh*16 + blk
  int bh = gid >> 4, blk = gid & 15;
  float s = slope[bh & 15];
  __shared__ unsigned short kT[128][72];
  __shared__ unsigned short vT[128][72];
  int tid = threadIdx.x, w = tid >> 6, lane = tid & 63;
  int wrow = (w >> 1) * 64, wcol = (w & 1) * 64;
  f32x4 acc[4][4];
#pragma unroll
  for (int m = 0; m < 4; m++)
#pragma unroll
    for (int n = 0; n < 4; n++) acc[m][n] = (f32x4)0.f;
  const unsigned short* kb = kk + ((size_t)bh * 4096 + blk * 256) * 128;
  const unsigned short* vb = vv + ((size_t)bh * 4096 + blk * 256) * 128;
  int tt = tid & 63, c0 = (tid >> 6) * 32;
  for (int tc = 0; tc < 4; ++tc) {
    __syncthreads();
    int tg = tc * 64 + tt;
    float kd = __expf(-s * (float)(255 - tg));
#pragma unroll
    for (int g = 0; g < 4; ++g) {
      int c = c0 + g * 8;
      short8 k8 = *(const short8*)(kb + (size_t)tg * 128 + c);
      short8 v8 = *(const short8*)(vb + (size_t)tg * 128 + c);
#pragma unroll
      for (int j = 0; j < 8; ++j) {
        kT[c + j][tt] = f2b(b2f((unsigned short)k8[j]) * kd);
        vT[c + j][tt] = (unsigned short)v8[j];
      }
    }
    __syncthreads();
#pragma unroll
    for (int kx = 0; kx < 64; kx += 32) {
      int ko = kx + (lane >> 4) * 8;
      short8 af[4], bfr[4];
#pragma unroll
      for (int m = 0; m < 4; m++) af[m] = *(const short8*)&vT[wrow + m * 16 + (lane & 15)][ko];
#pragma unroll
      for (int n = 0; n < 4; n++) bfr[n] = *(const short8*)&kT[wcol + n * 16 + (lane & 15)][ko];
#pragma unroll
      for (int m = 0; m < 4; m++)
#pragma unroll
        for (int n = 0; n < 4; n++) acc[m][n] = MFMA(af[m], bfr[n], acc[m][n]);
    }
  }
  unsigned short* op = kvT + (size_t)gid * 16384;
#pragma unroll
  for (int m = 0; m < 4; m++)
#pragma unroll
    for (int r = 0; r < 4; r++) {
      int e = wrow + m * 16 + (lane >> 4) * 4 + r;
#pragma unroll
      for (int n = 0; n < 4; n++) {
        int d = wcol + n * 16 + (lane & 15);
        op[e * 128 + d] = f2b(acc[m][n][r]);
      }
    }
}

// ---------------- decay prefix scan over blocks (in place: kvT[i] := state before block i) ----------------
__global__ void k_scan(unsigned short* kvT, const float* __restrict__ slope) {
  int gid = blockIdx.x;  // 2048
  int bh = gid >> 6;
  int eo = (gid & 63) * 256 + threadIdx.x;  // 0..16383
  float s = slope[bh & 15];
  float bd = __expf(-s * 256.f);
  float st = 0.f;
  size_t base = (size_t)bh * 16 * 16384 + eo;
#pragma unroll
  for (int i = 0; i < 16; ++i) {
    unsigned short c = kvT[base + (size_t)i * 16384];
    kvT[base + (size_t)i * 16384] = f2b(st);
    st = bd * st + b2f(c);
  }
}

// ---------------- per-block attention output (merged 256-row block, 512 threads) --------
// One block per (bh, blk): K/V staged ONCE (vs twice in the 2-half version), all 8 waves
// cooperate on staging; wave w computes rows mm0 = w*32, gated per chunk. LDS pool 72704B:
// k_sh[64][136] + vT_sh[128][72] + s_sh[8][32][72]; after final barrier reused as a
// [256][128] bf16 repack tile (65536B). Write col (ni*16+l15)^(l4<<4); read chunk c of row
// rl at (c*8)^(((rl>>2)&3)<<4); 16 lanes stream one contiguous 256B head-row.
__global__ __launch_bounds__(512) void k_attn(const unsigned short* __restrict__ q,
                                              const unsigned short* __restrict__ kk,
                                              const unsigned short* __restrict__ vv,
                                              const unsigned short* __restrict__ kvT,
                                              const float* __restrict__ slope,
                                              unsigned short* __restrict__ attn) {
  int gid = blockIdx.x;  // 512 = bh*16 + blk
  int blk = gid & 15, bh = gid >> 4;
  float s = slope[bh & 15];
  __shared__ char pool[72704] __attribute__((aligned(16)));
  auto k_sh = (unsigned short(*)[136])pool;                 // [64][136]
  auto vT_sh = (unsigned short(*)[72])(pool + 17408);       // [128][72]
  auto s_sh = (unsigned short(*)[32][72])(pool + 35840);    // [8][32][72]
  unsigned short* osm = (unsigned short*)pool;              // [256][128] after final barrier
  int tid = threadIdx.x, w = tid >> 6, lane = tid & 63;
  int mm0 = w * 32;  // wave's first within-block row
  const unsigned short* qb = q + ((size_t)bh * 4096 + blk * 256) * 128;
  const unsigned short* kvb = kvT + (size_t)(bh * 16 + blk) * 16384;
  f32x4 acc[2][8];
#pragma unroll
  for (int m = 0; m < 2; m++)
#pragma unroll
    for (int n = 0; n < 8; n++) acc[m][n] = (f32x4)0.f;
  // inter-block: (q) @ KV_pre   (row-scale by q_decay afterwards)
#pragma unroll
  for (int kx = 0; kx < 128; kx += 32) {
    int ko = kx + (lane >> 4) * 8;
    short8 af[2], bfr[8];
#pragma unroll
    for (int mi = 0; mi < 2; mi++)
      af[mi] = *(const short8*)(qb + (size_t)(mm0 + mi * 16 + (lane & 15)) * 128 + ko);
#pragma unroll
    for (int ni = 0; ni < 8; ni++)
      bfr[ni] = *(const short8*)(kvb + (size_t)(ni * 16 + (lane & 15)) * 128 + ko);
#pragma unroll
    for (int mi = 0; mi < 2; mi++)
#pragma unroll
      for (int ni = 0; ni < 8; ni++) acc[mi][ni] = MFMA(af[mi], bfr[ni], acc[mi][ni]);
  }
#pragma unroll
  for (int mi = 0; mi < 2; mi++)
#pragma unroll
    for (int r = 0; r < 4; r++) {
      float qd = __expf(-s * (float)(mm0 + mi * 16 + (lane >> 4) * 4 + r + 1));
#pragma unroll
      for (int ni = 0; ni < 8; ni++) acc[mi][ni][r] *= qd;
    }
  // intra-block: masked quadratic attention, 64-wide t-chunks (staged once per block)
  for (int tc = 0; tc < 4; ++tc) {
    __syncthreads();
    {  // stage K chunk rows [t][d]: 512 thr x 2 short8
      int t2 = tid >> 3, c = (tid & 7) * 16;
      const unsigned short* kp = kk + ((size_t)bh * 4096 + blk * 256 + tc * 64 + t2) * 128 + c;
#pragma unroll
      for (int g = 0; g < 2; ++g) *(short8*)&k_sh[t2][c + g * 8] = *(const short8*)(kp + g * 8);
    }
    {  // stage V^T chunk [e][t]: 512 thr x 2 short8 scattered
      int t2 = tid & 63, e0 = (tid >> 6) * 16;
      const unsigned short* vp = vv + ((size_t)bh * 4096 + blk * 256 + tc * 64 + t2) * 128 + e0;
#pragma unroll
      for (int g = 0; g < 2; ++g) {
        short8 v8 = *(const short8*)(vp + g * 8);
#pragma unroll
        for (int j = 0; j < 8; ++j) vT_sh[e0 + g * 8 + j][t2] = (unsigned short)v8[j];
      }
    }
    __syncthreads();
    if (tc * 64 <= mm0 + 31) {
      f32x4 sa[2][4];
#pragma unroll
      for (int m = 0; m < 2; m++)
#pragma unroll
        for (int n = 0; n < 4; n++) sa[m][n] = (f32x4)0.f;
#pragma unroll
      for (int kx = 0; kx < 128; kx += 32) {
        int ko = kx + (lane >> 4) * 8;
        short8 af[2], bfr[4];
#pragma unroll
        for (int mi = 0; mi < 2; mi++)
          af[mi] = *(const short8*)(qb + (size_t)(mm0 + mi * 16 + (lane & 15)) * 128 + ko);
#pragma unroll
        for (int ni = 0; ni < 4; ni++) bfr[ni] = *(const short8*)&k_sh[ni * 16 + (lane & 15)][ko];
#pragma unroll
        for (int mi = 0; mi < 2; mi++)
#pragma unroll
          for (int ni = 0; ni < 4; ni++) sa[mi][ni] = MFMA(af[mi], bfr[ni], sa[mi][ni]);
      }
      // mask * decay, to bf16, into per-wave S tile
#pragma unroll
      for (int mi = 0; mi < 2; mi++)
#pragma unroll
        for (int ni = 0; ni < 4; ni++)
#pragma unroll
          for (int r = 0; r < 4; r++) {
            int mm = mm0 + mi * 16 + (lane >> 4) * 4 + r;
            int ttg = tc * 64 + ni * 16 + (lane & 15);
            int diff = mm - ttg;
            float val = (diff >= 0) ? sa[mi][ni][r] * __expf(-s * (float)diff) : 0.f;
            s_sh[w][mi * 16 + (lane >> 4) * 4 + r][ni * 16 + (lane & 15)] = f2b(val);
          }
      // O += S @ V
#pragma unroll
      for (int k2 = 0; k2 < 64; k2 += 32) {
        int ko2 = k2 + (lane >> 4) * 8;
        short8 a2[2];
#pragma unroll
        for (int mi = 0; mi < 2; mi++)
          a2[mi] = *(const short8*)&s_sh[w][mi * 16 + (lane & 15)][ko2];
#pragma unroll
        for (int ni = 0; ni < 8; ni++) {
          short8 b2 = *(const short8*)&vT_sh[ni * 16 + (lane & 15)][ko2];
#pragma unroll
          for (int mi = 0; mi < 2; mi++) acc[mi][ni] = MFMA(a2[mi], b2, acc[mi][ni]);
        }
      }
    }
  }
  // ---- output repack: acc -> swizzled LDS [256][128] -> coalesced 16B stores ----
  BARRIER;  // all s_sh/vT_sh reads done before pool reuse
  int l15 = lane & 15, l4 = lane >> 4;
#pragma unroll
  for (int mi = 0; mi < 2; mi++)
#pragma unroll
    for (int ni = 0; ni < 8; ni++) {
      int cx = ((ni * 16 + l15) ^ (l4 << 4));
      int rowb = w * 32 + mi * 16 + l4 * 4;
#pragma unroll
      for (int r = 0; r < 4; r++) osm[(rowb + r) * 128 + cx] = f2b(acc[mi][ni][r]);
    }
  BARRIER;
  {
    int b = bh >> 4, h = bh & 15;
    int rl0 = tid >> 4;       // 0..31
    int c = tid & 15;         // 8-short chunk index within the 128-col head row
#pragma unroll
    for (int it = 0; it < 8; ++it) {
      int rl = it * 32 + rl0;
      int e = (c * 8) ^ (((rl >> 2) & 3) << 4);  // inverse of write swizzle
      short8 v8 = *(const short8*)(osm + rl * 128 + e);
      size_t rowp = ((size_t)b * 4096 + blk * 256 + rl) * 2048 + h * 128 + c * 8;
      *(short8*)(attn + rowp) = v8;
    }
  }
}

// ---------------- RMSNorm + gate ----------------
__global__ __launch_bounds__(256) void k_norm(const unsigned short* __restrict__ attn,
                                              const unsigned short* __restrict__ gate,
                                              const float* __restrict__ nw,
                                              unsigned short* __restrict__ y) {
  int row = blockIdx.x;  // 8192
  int tid = threadIdx.x, w = tid >> 6, lane = tid & 63;
  const unsigned short* ap = attn + (size_t)row * 2048 + tid * 8;
  const unsigned short* gp = gate + (size_t)row * 2048 + tid * 8;
  short8 a8 = *(const short8*)ap;
  float vals[8];
  float ss = 0.f;
#pragma unroll
  for (int j = 0; j < 8; ++j) {
    vals[j] = b2f((unsigned short)a8[j]);
    ss += vals[j] * vals[j];
  }
#pragma unroll
  for (int off = 32; off > 0; off >>= 1) ss += __shfl_down(ss, off, 64);
  __shared__ float red[4];
  if (lane == 0) red[w] = ss;
  __syncthreads();
  float tot = red[0] + red[1] + red[2] + red[3];
  float rms = rsqrtf(tot * (1.f / 2048.f) + 1.1920929e-07f);
  short8 g8 = *(const short8*)gp;
  short8 o;
#pragma unroll
  for (int j = 0; j < 8; ++j)
    o[j] = (short)f2b(vals[j] * rms * nw[tid * 8 + j] * b2f((unsigned short)g8[j]));
  *(short8*)(y + (size_t)row * 2048 + tid * 8) = o;
}

extern "C" void kernel_launch(void* const* d_in, const int* in_sizes, int n_in, void* d_out,
                              int out_size, void* d_ws, size_t ws_size, hipStream_t stream) {
  const float* x = (const float*)d_in[0];
  const float* slope = (const float*)d_in[1];
  const float* Wqkv = (const float*)d_in[2];
  const float* Wg = (const float*)d_in[3];
  const float* nw = (const float*)d_in[4];
  const float* Wo = (const float*)d_in[5];
  float* out = (float*)d_out;

  unsigned short* q = (unsigned short*)d_ws;               // 16,777,216 elems
  unsigned short* k = q + 16777216;                        // 16,777,216
  unsigned short* v = k + 16777216;                        // 16,777,216
  unsigned short* gate = v + 16777216;                     // 16,777,216
  unsigned short* xb = gate + 16777216;                    // 16,777,216
  unsigned short* wqkvb = xb + 16777216;                   // 12,582,912
  unsigned short* wgb = wqkvb + 12582912;                  // 4,194,304
  unsigned short* wob = wgb + 4194304;                     // 4,194,304
  unsigned short* kvT = wob + 4194304;                     // 8,388,608
  unsigned short* attn = wqkvb;  // alias: wqkvb+wgb dead after GEMM1 (exactly 16,777,216)
  unsigned short* y = xb;        // alias: xb dead after GEMM1

  k_f2b4<<<36864, 256, 0, stream>>>(x, Wqkv, Wg, Wo, xb);  // xb..wob contiguous

  k_gemm<0><<<1024, 512, 0, stream>>>(xb, wqkvb, wgb, q, k, v, gate, nullptr);
  k_kvblk<<<512, 256, 0, stream>>>(k, v, slope, kvT);
  k_scan<<<2048, 256, 0, stream>>>(kvT, slope);
  k_attn<<<512, 512, 0, stream>>>(q, k, v, kvT, slope, attn);
  k_norm<<<8192, 256, 0, stream>>>(attn, gate, nw, y);
  k_gemm<1><<<256, 512, 0, stream>>>(y, wob, nullptr, nullptr, nullptr, nullptr, nullptr, out);
}